// Round 7
// baseline (1700.413 us; speedup 1.0000x reference)
//
#include <hip/hip_runtime.h>
#include <cstdint>
#include <climits>
#include <math.h>

#define NN 50000
#define EE 1600000
#define ET (EE + NN)   // real edges + one self-loop per node
#define GG 512
#define NEG_SLOPE 0.2f
#define NB 196          // ceil(NN/256) scan blocks

typedef _Float16 half2v __attribute__((ext_vector_type(2)));

__device__ __forceinline__ uint32_t packh2(float a, float b) {
    union { half2v h; uint32_t u; } c;
    c.h = half2v{(_Float16)a, (_Float16)b};
    return c.u;
}
__device__ __forceinline__ float2 uph(uint32_t u) {
    union { uint32_t u; half2v h; } c;
    c.u = u;
    return make_float2((float)c.h.x, (float)c.h.y);
}
__device__ __forceinline__ uint32_t pkadd(uint32_t a, uint32_t b) {
    union { uint32_t u; half2v h; } x, y, z;
    x.u = a; y.u = b;
    z.h = x.h + y.h;    // v_pk_add_f16
    return z.u;
}
__device__ __forceinline__ float fdot2u(uint32_t a, uint32_t b, float c) {
    union { uint32_t u; half2v h; } ua, ub;
    ua.u = a; ub.u = b;
    return __builtin_amdgcn_fdot2(ua.h, ub.h, c, false);
}
__device__ __forceinline__ float rlanef(float v, int l) {
    return __int_as_float(__builtin_amdgcn_readlane(__float_as_int(v), l));
}

// ---------- degree histogram ----------
__global__ void k_hist(const int* __restrict__ dst, int* __restrict__ hist) {
    int e = blockIdx.x * blockDim.x + threadIdx.x;
    if (e < EE) atomicAdd(&hist[dst[e]], 1);
}

// ---------- CSR build ----------
__global__ void k_scan_a(const int* __restrict__ hist, int* __restrict__ bsum) {
    __shared__ int tmp[256];
    int i = blockIdx.x * 256 + threadIdx.x;
    tmp[threadIdx.x] = (i < NN) ? hist[i] : 0;
    __syncthreads();
    for (int d = 128; d; d >>= 1) {
        if (threadIdx.x < d) tmp[threadIdx.x] += tmp[threadIdx.x + d];
        __syncthreads();
    }
    if (threadIdx.x == 0) bsum[blockIdx.x] = tmp[0];
}

__global__ void k_scan_b(int* __restrict__ bsum, int* __restrict__ rowptr) {
    __shared__ int tmp[256];
    int t = threadIdx.x;
    int v = (t < NB) ? bsum[t] : 0;
    tmp[t] = v;
    __syncthreads();
    for (int d = 1; d < 256; d <<= 1) {
        int u = (t >= d) ? tmp[t - d] : 0;
        __syncthreads();
        tmp[t] += u;
        __syncthreads();
    }
    if (t < NB) bsum[t] = tmp[t] - v;        // exclusive
    if (t == 255) rowptr[NN] = tmp[255];     // total == EE
}

// rowptr + cursor init fused
__global__ void k_scan_c(const int* __restrict__ hist, const int* __restrict__ bsum,
                         int* __restrict__ rowptr, int* __restrict__ cursor) {
    __shared__ int tmp[256];
    int i = blockIdx.x * 256 + threadIdx.x;
    int v = (i < NN) ? hist[i] : 0;
    tmp[threadIdx.x] = v;
    __syncthreads();
    for (int d = 1; d < 256; d <<= 1) {
        int t = (threadIdx.x >= d) ? tmp[threadIdx.x - d] : 0;
        __syncthreads();
        tmp[threadIdx.x] += t;
        __syncthreads();
    }
    if (i < NN) {
        int rp = tmp[threadIdx.x] - v + bsum[blockIdx.x];
        rowptr[i] = rp;
        cursor[i] = rp;
    }
}

// ---------- scatter + csr_src + fp16 AoS ea pack, one pass ----------
__global__ void k_scatter(const int* __restrict__ srcv, const int* __restrict__ dstv,
                          const float* __restrict__ ea, int* __restrict__ cursor,
                          int* __restrict__ csr_src, uint32_t* __restrict__ eaa) {
    int e = blockIdx.x * blockDim.x + threadIdx.x;
    if (e >= EE) return;
    int d = dstv[e];
    int p = atomicAdd(&cursor[d], 1);
    csr_src[p] = srcv[e];
    const float* r = ea + (size_t)e * 18;
    uint32_t o[12];
#pragma unroll
    for (int kk = 0; kk < 9; kk++) {
        float2 q = *(const float2*)(r + 2 * kk);
        o[kk] = packh2(q.x, q.y);
    }
    o[9] = o[10] = o[11] = 0;
    uint4* dst = (uint4*)(eaa + (size_t)p * 12);
    dst[0] = *(uint4*)&o[0];
    dst[1] = *(uint4*)&o[4];
    dst[2] = *(uint4*)&o[8];
}

// ---------- self-loop edge attr = mean of incoming ea; append virtual entries ----------
__global__ void __launch_bounds__(256)
k_loop2(const int* __restrict__ rowptr, uint32_t* __restrict__ eaa) {
    const int lane = threadIdx.x & 63;
    int wid = blockIdx.x * (blockDim.x >> 6) + (threadIdx.x >> 6);
    int nw = gridDim.x * (blockDim.x >> 6);

    for (int i = wid; i < NN; i += nw) {
        int beg = __builtin_amdgcn_readfirstlane(rowptr[i]);
        int end = __builtin_amdgcn_readfirstlane(rowptr[i + 1]);
        float s[18];
#pragma unroll
        for (int j = 0; j < 18; j++) s[j] = 0.f;
        for (int cs = beg; cs < end; cs += 64) {
            int cnt = end - cs; if (cnt > 64) cnt = 64;
            if (lane < cnt) {
                const uint32_t* pe = eaa + (size_t)(cs + lane) * 12;
                uint4 a = *(const uint4*)pe;
                uint4 b = *(const uint4*)(pe + 4);
                uint32_t c = pe[8];
                uint32_t w[9] = {a.x, a.y, a.z, a.w, b.x, b.y, b.z, b.w, c};
#pragma unroll
                for (int kk = 0; kk < 9; kk++) {
                    float2 q = uph(w[kk]);
                    s[2 * kk] += q.x; s[2 * kk + 1] += q.y;
                }
            }
        }
#pragma unroll
        for (int j = 0; j < 18; j++) {
#pragma unroll
            for (int off = 32; off; off >>= 1) s[j] += __shfl_xor(s[j], off, 64);
        }
        if (lane == 0) {
            int deg = end - beg;
            float rd = (deg > 0) ? 1.0f / (float)deg : 0.0f;
            uint32_t o[12];
#pragma unroll
            for (int kk = 0; kk < 9; kk++) o[kk] = packh2(s[2 * kk] * rd, s[2 * kk + 1] * rd);
            o[9] = o[10] = o[11] = 0;
            uint4* dst = (uint4*)(eaa + (size_t)(EE + i) * 12);
            dst[0] = *(uint4*)&o[0];
            dst[1] = *(uint4*)&o[4];
            dst[2] = *(uint4*)&o[8];
        }
    }
}

// ---------- pack WeT (zero-padded to CP cols): per col: 9 fp16-pair dwords + att ----------
__global__ void k_pack_wet(const float* __restrict__ We, const float* __restrict__ att,
                           uint32_t* __restrict__ WeT, int C, int CP) {
    int t = blockIdx.x * blockDim.x + threadIdx.x;
    if (t >= CP * 10) return;
    int c = t / 10, kk = t - c * 10;
    int g = c >> 2, j = c & 3;
    uint32_t v = 0;
    if (c < C) {
        if (kk < 9) v = packh2(We[(2 * kk) * C + c], We[(2 * kk + 1) * C + c]);
        else v = __float_as_uint(att[c]);
    }
    WeT[g * 40 + j * 10 + kk] = v;
}

// ---------- combine Wl|Wr into padded Wc [K x NP], biases into bc [NP] ----------
__global__ void k_combine_w(const float* __restrict__ Wl, const float* __restrict__ bl,
                            const float* __restrict__ Wr, const float* __restrict__ br,
                            float* __restrict__ Wc, float* __restrict__ bc,
                            int K, int C, int NP) {
    int t = blockIdx.x * blockDim.x + threadIdx.x;
    if (t < K * NP) {
        int k = t / NP, n = t - k * NP;
        float v = 0.0f;
        if (n < C) v = Wl[k * C + n];
        else if (n < 2 * C) v = Wr[k * C + n - C];
        Wc[t] = v;
    }
    if (t < NP) {
        float v = 0.0f;
        if (t < C) v = bl[t];
        else if (t < 2 * C) v = br[t - C];
        bc[t] = v;
    }
}

// ---------- tiled dual GEMM -> xl16/xr16 (packed fp16, padded pitch RL) ----------
template <int KK, int NP, int C, int RL>
__global__ void __launch_bounds__(256)
k_gemm_dual(const float* __restrict__ A, const float* __restrict__ Wc,
            const float* __restrict__ bc,
            uint32_t* __restrict__ xl16, uint32_t* __restrict__ xr16) {
    constexpr int BM = 64, BN = 64, BK = 16;
    __shared__ float As[BK][BM];
    __shared__ float Ws[BK][BN];
    const int tidx = threadIdx.x;
    const int tx = tidx & 15;
    const int ty = tidx >> 4;
    const int m0 = blockIdx.x * BM;
    const int n0 = blockIdx.y * BN;

    float acc[4][4];
#pragma unroll
    for (int i2 = 0; i2 < 4; i2++)
#pragma unroll
        for (int j2 = 0; j2 < 4; j2++) acc[i2][j2] = 0.0f;

    for (int k0 = 0; k0 < KK; k0 += BK) {
        {
            int m = tidx >> 2;
            int kq = (tidx & 3) * 4;
            float4 v = make_float4(0.f, 0.f, 0.f, 0.f);
            if (m0 + m < NN && k0 + kq < KK)
                v = *(const float4*)(A + (size_t)(m0 + m) * KK + k0 + kq);
            As[kq + 0][m] = v.x; As[kq + 1][m] = v.y;
            As[kq + 2][m] = v.z; As[kq + 3][m] = v.w;
        }
        {
            int k = tidx >> 4;
            int nq = (tidx & 15) * 4;
            float4 v = make_float4(0.f, 0.f, 0.f, 0.f);
            if (k0 + k < KK)
                v = *(const float4*)(Wc + (size_t)(k0 + k) * NP + n0 + nq);
            *(float4*)&Ws[k][nq] = v;
        }
        __syncthreads();
#pragma unroll
        for (int k = 0; k < BK; k++) {
            float a[4], b[4];
            *(float4*)a = *(const float4*)&As[k][ty * 4];
            *(float4*)b = *(const float4*)&Ws[k][tx * 4];
#pragma unroll
            for (int i2 = 0; i2 < 4; i2++)
#pragma unroll
                for (int j2 = 0; j2 < 4; j2++) acc[i2][j2] += a[i2] * b[j2];
        }
        __syncthreads();
    }

    const int n = n0 + tx * 4;
    float4 bcv = *(const float4*)(bc + n);
#pragma unroll
    for (int i2 = 0; i2 < 4; i2++) {
        int m = m0 + ty * 4 + i2;
        if (m >= NN) continue;
        float4 o = make_float4(acc[i2][0] + bcv.x, acc[i2][1] + bcv.y,
                               acc[i2][2] + bcv.z, acc[i2][3] + bcv.w);
        uint2 p;
        p.x = packh2(o.x, o.y);
        p.y = packh2(o.z, o.w);
        if (n < C)          *(uint2*)(xl16 + (size_t)m * RL + n / 2) = p;
        else if (n < 2 * C) *(uint2*)(xr16 + (size_t)m * RL + (n - C) / 2) = p;
    }
}

// ---------- fused GAT: wave per node, 32-row LDS, dual sub-phase aggregation ----------
// Lane = edge within 64-edge group. Virtual self-loop at position `end` of [beg, end+1).
// Score from registers; aggregation via strided column map (conflict-free).
template <int C, int VEC, int RELU>
__global__ void __launch_bounds__(64)
k_gat(const int* __restrict__ rowptr, const int* __restrict__ csr_src,
      const uint32_t* __restrict__ eaa, const uint32_t* __restrict__ WeT,
      const uint32_t* __restrict__ xl16, const uint32_t* __restrict__ xr16,
      const float* __restrict__ bias, float* __restrict__ out) {
    constexpr int RL = ((C / 2) + 3) & ~3;   // global row pitch (dwords): 52 / 100
    constexpr int LP = RL + 1;               // LDS pitch, odd -> conflict-free b32
    constexpr int NQ = RL / 4;               // uint4 per row: 13 / 25
    constexpr int NL = C / VEC;              // active agg lanes: 50
    constexpr int DW = VEC / 2;              // dwords per agg lane: 1 / 2
    __shared__ uint32_t s_rows[32 * LP];     // HALF-group row buffer
    __shared__ uint32_t s_xr[RL];
    const int lane = threadIdx.x;

    for (int i = blockIdx.x; i < NN; i += gridDim.x) {
        int beg = __builtin_amdgcn_readfirstlane(rowptr[i]);
        int end = __builtin_amdgcn_readfirstlane(rowptr[i + 1]);
        int endp = end + 1;   // + virtual self edge

        // xr[dst] row -> LDS once per node (coalesced; broadcast-read later)
        for (int j = lane; j < RL; j += 64) s_xr[j] = xr16[(size_t)i * RL + j];

        float m = -INFINITY, z = 0.0f;
        float acc[VEC];
#pragma unroll
        for (int j = 0; j < VEC; j++) acc[j] = 0.0f;

        for (int cs = beg; cs < endp; cs += 64) {
            int cnt = endp - cs; if (cnt > 64) cnt = 64;
            int pos = cs + lane;
            bool ae = pos < endp;

            // ---- gather row + ea into regs (all 64 lanes, pinned issue) ----
            uint4 st[NQ];
            uint32_t ear[9];
            int sx = i;
            if (ae) {
                sx = (pos < end) ? csr_src[pos] : i;
                size_t eidx = (pos < end) ? (size_t)pos : (size_t)(EE + i);
                const uint4* pr = (const uint4*)(xl16 + (size_t)sx * RL);
#pragma unroll
                for (int q = 0; q < NQ; q++) st[q] = pr[q];
                const uint32_t* pe = eaa + eidx * 12;
                uint4 e0 = *(const uint4*)pe;
                uint4 e1 = *(const uint4*)(pe + 4);
                ear[0] = e0.x; ear[1] = e0.y; ear[2] = e0.z; ear[3] = e0.w;
                ear[4] = e1.x; ear[5] = e1.y; ear[6] = e1.z; ear[7] = e1.w;
                ear[8] = pe[8];
            }
            __builtin_amdgcn_sched_barrier(0);   // pin: all loads issued first

            // ---- phase-A rows (lanes 0..31) -> LDS ----
            if (lane < 32 && ae) {
#pragma unroll
                for (int q = 0; q < NQ; q++) {
                    s_rows[lane * LP + 4 * q + 0] = st[q].x;
                    s_rows[lane * LP + 4 * q + 1] = st[q].y;
                    s_rows[lane * LP + 4 * q + 2] = st[q].z;
                    s_rows[lane * LP + 4 * q + 3] = st[q].w;
                }
            }

            // ---- in-lane score from registers (WeT uniform -> scalar loads) ----
            float s = -INFINITY;
            if (ae) {
                float sc = 0.0f;
#pragma unroll
                for (int q = 0; q < NQ; q++) {
                    uint32_t rv[4] = {st[q].x, st[q].y, st[q].z, st[q].w};
#pragma unroll
                    for (int j = 0; j < 4; j++) {
                        const int d = 4 * q + j;
                        uint32_t u = pkadd(rv[j], s_xr[d]);
                        float2 f = uph(u);
                        const uint32_t* wg = WeT + (d >> 1) * 40 + (d & 1) * 20;
                        float w0 = 0.0f, w1 = 0.0f;
#pragma unroll
                        for (int kk = 0; kk < 9; kk++) {
                            w0 = fdot2u(ear[kk], wg[kk], w0);
                            w1 = fdot2u(ear[kk], wg[10 + kk], w1);
                        }
                        float u0 = f.x + w0, u1 = f.y + w1;
                        float h0 = fmaxf(u0, NEG_SLOPE * u0);
                        float h1v = fmaxf(u1, NEG_SLOPE * u1);
                        sc = fmaf(__uint_as_float(wg[9]), h0, sc);
                        sc = fmaf(__uint_as_float(wg[19]), h1v, sc);
                    }
                }
                s = sc;
            }

            // ---- per-group online softmax ----
            float pmax = s;
#pragma unroll
            for (int off = 32; off; off >>= 1) pmax = fmaxf(pmax, __shfl_xor(pmax, off, 64));
            float mn = fmaxf(m, pmax);
            float sca = __expf(m - mn);     // m=-inf first group -> 0
            float pe = __expf(s - mn);      // inactive lanes: exp(-inf)=0
            float zc = pe;
#pragma unroll
            for (int off = 32; off; off >>= 1) zc += __shfl_xor(zc, off, 64);
            z = z * sca + zc;
            m = mn;
#pragma unroll
            for (int j = 0; j < VEC; j++) acc[j] *= sca;

            // ---- phase-B re-gather (lanes 32..63, L1/L2-hot), overlaps agg-A ----
            const bool beB = ae && (lane >= 32);
            if (beB) {
                const uint4* pr = (const uint4*)(xl16 + (size_t)sx * RL);
#pragma unroll
                for (int q = 0; q < NQ; q++) st[q] = pr[q];
            }
            __builtin_amdgcn_sched_barrier(0);   // pin: B loads issued before agg-A

            // ---- aggregate phase A from LDS (strided cols: conflict-free) ----
            int cntA = cnt < 32 ? cnt : 32;
            if (lane < NL) {
                for (int e = 0; e < cntA; e++) {
                    float a = rlanef(pe, e);
#pragma unroll
                    for (int q = 0; q < DW; q++) {
                        float2 f = uph(s_rows[e * LP + q * NL + lane]);
                        acc[2 * q] = fmaf(a, f.x, acc[2 * q]);
                        acc[2 * q + 1] = fmaf(a, f.y, acc[2 * q + 1]);
                    }
                }
            }

            // ---- phase B: write rows 32..cnt-1, aggregate ----
            if (cnt > 32) {
                if (beB) {
#pragma unroll
                    for (int q = 0; q < NQ; q++) {
                        s_rows[(lane - 32) * LP + 4 * q + 0] = st[q].x;
                        s_rows[(lane - 32) * LP + 4 * q + 1] = st[q].y;
                        s_rows[(lane - 32) * LP + 4 * q + 2] = st[q].z;
                        s_rows[(lane - 32) * LP + 4 * q + 3] = st[q].w;
                    }
                }
                if (lane < NL) {
                    int cntB = cnt - 32;
                    for (int e = 0; e < cntB; e++) {
                        float a = rlanef(pe, 32 + e);
#pragma unroll
                        for (int q = 0; q < DW; q++) {
                            float2 f = uph(s_rows[e * LP + q * NL + lane]);
                            acc[2 * q] = fmaf(a, f.x, acc[2 * q]);
                            acc[2 * q + 1] = fmaf(a, f.y, acc[2 * q + 1]);
                        }
                    }
                }
            }
        }

        if (lane < NL) {
            float rz = 1.0f / z;
#pragma unroll
            for (int q = 0; q < DW; q++) {
                int c0 = 2 * (q * NL + lane);
                float o0 = acc[2 * q] * rz + bias[c0];
                float o1 = acc[2 * q + 1] * rz + bias[c0 + 1];
                if (RELU) { o0 = fmaxf(o0, 0.0f); o1 = fmaxf(o1, 0.0f); }
                *(float2*)(out + (size_t)i * C + c0) = make_float2(o0, o1);
            }
        }
    }
}

// ---------- mean pooling per graph (batch_ids sorted); relu folded in ----------
__global__ void k_pool(const float* __restrict__ h, const int* __restrict__ batch,
                       float* __restrict__ pooled) {
    int g = blockIdx.x;
    int lo = 0, hi = NN;
    while (lo < hi) { int mid = (lo + hi) >> 1; if (batch[mid] < g) lo = mid + 1; else hi = mid; }
    int start = lo;
    lo = start; hi = NN;
    while (lo < hi) { int mid = (lo + hi) >> 1; if (batch[mid] < g + 1) lo = mid + 1; else hi = mid; }
    int end = lo;
    float cnt = (float)(end - start);
    int c = threadIdx.x;
    if (c < 200) {
        float acc = 0.0f;
        for (int i = start; i < end; i++) acc += fmaxf(h[(size_t)i * 200 + c], 0.0f);
        pooled[g * 200 + c] = acc / fmaxf(cnt, 1.0f);
    }
}

// ---------- small dense layers on [G, *] ----------
__global__ void k_mlp(const float* __restrict__ X, const float* __restrict__ W,
                      const float* __restrict__ b, float* __restrict__ Y,
                      int Cin, int Cout, int do_relu) {
    int t = blockIdx.x * blockDim.x + threadIdx.x;
    if (t >= GG * Cout) return;
    int g = t / Cout, j = t - g * Cout;
    const float* xrow = X + (size_t)g * Cin;
    float acc = b[j];
    for (int k = 0; k < Cin; k++) acc += xrow[k] * W[k * Cout + j];
    if (do_relu) acc = fmaxf(acc, 0.0f);
    Y[t] = acc;
}

extern "C" void kernel_launch(void* const* d_in, const int* in_sizes, int n_in,
                              void* d_out, int out_size, void* d_ws, size_t ws_size,
                              hipStream_t stream) {
    const float* x   = (const float*)d_in[0];
    const int*   ei  = (const int*)d_in[1];
    const float* ea  = (const float*)d_in[2];
    const int*   bat = (const int*)d_in[3];
    const float* W1l = (const float*)d_in[4];  const float* b1l = (const float*)d_in[5];
    const float* W1r = (const float*)d_in[6];  const float* b1r = (const float*)d_in[7];
    const float* W1e = (const float*)d_in[8];
    const float* a1  = (const float*)d_in[9];  const float* c1  = (const float*)d_in[10];
    const float* W2l = (const float*)d_in[11]; const float* b2l = (const float*)d_in[12];
    const float* W2r = (const float*)d_in[13]; const float* b2r = (const float*)d_in[14];
    const float* W2e = (const float*)d_in[15];
    const float* a2  = (const float*)d_in[16]; const float* c2  = (const float*)d_in[17];
    const float* W3  = (const float*)d_in[18]; const float* b3  = (const float*)d_in[19];
    const float* F1  = (const float*)d_in[20]; const float* bf1 = (const float*)d_in[21];
    const float* F2  = (const float*)d_in[22]; const float* bf2 = (const float*)d_in[23];
    const float* F3  = (const float*)d_in[24]; const float* bf3 = (const float*)d_in[25];

    const int* srcv = ei;        // edge_index[0]
    const int* dstv = ei + EE;   // edge_index[1]

    float* W = (float*)d_ws;
    size_t off = 0;
    int*      hist    = (int*)(W + off); off += NN;
    float*    h1      = W + off; off += (size_t)NN * 100;
    float*    h2      = W + off; off += (size_t)NN * 200;
    int*      rowptr  = (int*)(W + off); off += NN + 4;
    int*      cursor  = (int*)(W + off); off += NN;
    int*      bsum    = (int*)(W + off); off += 256;
    int*      csr_src = (int*)(W + off); off += ET;
    uint32_t* eaa     = (uint32_t*)(W + off); off += (size_t)ET * 12;
    uint32_t* xl16    = (uint32_t*)(W + off); off += (size_t)NN * 100;
    uint32_t* xr16    = (uint32_t*)(W + off); off += (size_t)NN * 100;
    uint32_t* WeT1    = (uint32_t*)(W + off); off += 26 * 40;
    uint32_t* WeT2    = (uint32_t*)(W + off); off += 50 * 40;
    float*    Wc1     = W + off; off += 16 * 256;
    float*    bc1     = W + off; off += 256;
    float*    Wc2     = W + off; off += 100 * 448;
    float*    bc2     = W + off; off += 448;
    float*    pooled  = W + off; off += (size_t)GG * 200;
    float*    p400    = W + off; off += (size_t)GG * 400;
    float*    y1      = W + off; off += (size_t)GG * 200;
    float*    y2      = W + off; off += (size_t)GG * 100;
    (void)ws_size; (void)n_in; (void)in_sizes; (void)out_size;

    const int B = 256;
    const int NODEB = 12500;   // k_loop2: 50000 waves, 1 node each

    // ---- degree histogram + CSR by dst; scatter also packs ea + src ----
    hipMemsetAsync(hist, 0, (size_t)NN * sizeof(int), stream);
    k_hist<<<(EE + B - 1) / B, B, 0, stream>>>(dstv, hist);
    k_scan_a<<<NB, 256, 0, stream>>>(hist, bsum);
    k_scan_b<<<1, 256, 0, stream>>>(bsum, rowptr);
    k_scan_c<<<NB, 256, 0, stream>>>(hist, bsum, rowptr, cursor);
    k_scatter<<<(EE + B - 1) / B, B, 0, stream>>>(srcv, dstv, ea, cursor, csr_src, eaa);
    k_loop2<<<NODEB, B, 0, stream>>>(rowptr, eaa);

    // ---- weight prep ----
    k_pack_wet<<<(104 * 10 + B - 1) / B, B, 0, stream>>>(W1e, a1, WeT1, 100, 104);
    k_pack_wet<<<(200 * 10 + B - 1) / B, B, 0, stream>>>(W2e, a2, WeT2, 200, 200);
    k_combine_w<<<(16 * 256 + B - 1) / B, B, 0, stream>>>(W1l, b1l, W1r, b1r, Wc1, bc1, 16, 100, 256);
    k_combine_w<<<(100 * 448 + B - 1) / B, B, 0, stream>>>(W2l, b2l, W2r, b2r, Wc2, bc2, 100, 200, 448);

    // ---- GAT layer 1: 16 -> 100 (RL = 52; pad dwords must be zero) ----
    hipMemsetAsync(xl16, 0, (size_t)NN * 52 * 4, stream);
    hipMemsetAsync(xr16, 0, (size_t)NN * 52 * 4, stream);
    {
        dim3 grid((NN + 63) / 64, 256 / 64);
        k_gemm_dual<16, 256, 100, 52><<<grid, 256, 0, stream>>>(x, Wc1, bc1, xl16, xr16);
    }
    k_gat<100, 2, 1><<<NN, 64, 0, stream>>>(rowptr, csr_src, eaa, WeT1, xl16, xr16, c1, h1);

    // ---- GAT layer 2: 100 -> 200 (RL = 100) ----
    {
        dim3 grid((NN + 63) / 64, 448 / 64);
        k_gemm_dual<100, 448, 200, 100><<<grid, 256, 0, stream>>>(h1, Wc2, bc2, xl16, xr16);
    }
    k_gat<200, 4, 0><<<NN, 64, 0, stream>>>(rowptr, csr_src, eaa, WeT2, xl16, xr16, c2, h2);

    // ---- pool (mean over graph, relu fused) then W3 + FFN ----
    k_pool<<<GG, 256, 0, stream>>>(h2, bat, pooled);
    k_mlp<<<(GG * 400 + B - 1) / B, B, 0, stream>>>(pooled, W3, b3, p400, 200, 400, 0);
    k_mlp<<<(GG * 200 + B - 1) / B, B, 0, stream>>>(p400, F1, bf1, y1, 400, 200, 1);
    k_mlp<<<(GG * 100 + B - 1) / B, B, 0, stream>>>(y1, F2, bf2, y2, 200, 100, 1);
    k_mlp<<<(GG * 100 + B - 1) / B, B, 0, stream>>>(y2, F3, bf3, (float*)d_out, 100, 100, 0);
}

// Round 8
// 1412.163 us; speedup vs baseline: 1.2041x; 1.2041x over previous
//
#include <hip/hip_runtime.h>
#include <cstdint>
#include <climits>
#include <math.h>

#define NN 50000
#define EE 1600000
#define ET (EE + NN)   // real edges + one self-loop per node
#define GG 512
#define NEG_SLOPE 0.2f
#define NB 196          // ceil(NN/256) scan blocks

typedef _Float16 half2v __attribute__((ext_vector_type(2)));

__device__ __forceinline__ uint32_t packh2(float a, float b) {
    union { half2v h; uint32_t u; } c;
    c.h = half2v{(_Float16)a, (_Float16)b};
    return c.u;
}
__device__ __forceinline__ float2 uph(uint32_t u) {
    union { uint32_t u; half2v h; } c;
    c.u = u;
    return make_float2((float)c.h.x, (float)c.h.y);
}
__device__ __forceinline__ uint32_t pkadd(uint32_t a, uint32_t b) {
    union { uint32_t u; half2v h; } x, y, z;
    x.u = a; y.u = b;
    z.h = x.h + y.h;    // v_pk_add_f16
    return z.u;
}
__device__ __forceinline__ float fdot2u(uint32_t a, uint32_t b, float c) {
    union { uint32_t u; half2v h; } ua, ub;
    ua.u = a; ub.u = b;
    return __builtin_amdgcn_fdot2(ua.h, ub.h, c, false);
}
__device__ __forceinline__ float rlanef(float v, int l) {
    return __int_as_float(__builtin_amdgcn_readlane(__float_as_int(v), l));
}

// ---------- degree histogram ----------
__global__ void k_hist(const int* __restrict__ dst, int* __restrict__ hist) {
    int e = blockIdx.x * blockDim.x + threadIdx.x;
    if (e < EE) atomicAdd(&hist[dst[e]], 1);
}

// ---------- CSR build ----------
__global__ void k_scan_a(const int* __restrict__ hist, int* __restrict__ bsum) {
    __shared__ int tmp[256];
    int i = blockIdx.x * 256 + threadIdx.x;
    tmp[threadIdx.x] = (i < NN) ? hist[i] : 0;
    __syncthreads();
    for (int d = 128; d; d >>= 1) {
        if (threadIdx.x < d) tmp[threadIdx.x] += tmp[threadIdx.x + d];
        __syncthreads();
    }
    if (threadIdx.x == 0) bsum[blockIdx.x] = tmp[0];
}

__global__ void k_scan_b(int* __restrict__ bsum, int* __restrict__ rowptr) {
    __shared__ int tmp[256];
    int t = threadIdx.x;
    int v = (t < NB) ? bsum[t] : 0;
    tmp[t] = v;
    __syncthreads();
    for (int d = 1; d < 256; d <<= 1) {
        int u = (t >= d) ? tmp[t - d] : 0;
        __syncthreads();
        tmp[t] += u;
        __syncthreads();
    }
    if (t < NB) bsum[t] = tmp[t] - v;        // exclusive
    if (t == 255) rowptr[NN] = tmp[255];     // total == EE
}

// rowptr + cursor init fused
__global__ void k_scan_c(const int* __restrict__ hist, const int* __restrict__ bsum,
                         int* __restrict__ rowptr, int* __restrict__ cursor) {
    __shared__ int tmp[256];
    int i = blockIdx.x * 256 + threadIdx.x;
    int v = (i < NN) ? hist[i] : 0;
    tmp[threadIdx.x] = v;
    __syncthreads();
    for (int d = 1; d < 256; d <<= 1) {
        int t = (threadIdx.x >= d) ? tmp[threadIdx.x - d] : 0;
        __syncthreads();
        tmp[threadIdx.x] += t;
        __syncthreads();
    }
    if (i < NN) {
        int rp = tmp[threadIdx.x] - v + bsum[blockIdx.x];
        rowptr[i] = rp;
        cursor[i] = rp;
    }
}

// ---------- scatter + csr_src/csr_dst + fp16 AoS ea pack, one pass ----------
__global__ void k_scatter(const int* __restrict__ srcv, const int* __restrict__ dstv,
                          const float* __restrict__ ea, int* __restrict__ cursor,
                          int* __restrict__ csr_src, int* __restrict__ csr_dst,
                          uint32_t* __restrict__ eaa) {
    int e = blockIdx.x * blockDim.x + threadIdx.x;
    if (e >= EE) return;
    int d = dstv[e];
    int p = atomicAdd(&cursor[d], 1);
    csr_src[p] = srcv[e];
    csr_dst[p] = d;
    const float* r = ea + (size_t)e * 18;
    uint32_t o[12];
#pragma unroll
    for (int kk = 0; kk < 9; kk++) {
        float2 q = *(const float2*)(r + 2 * kk);
        o[kk] = packh2(q.x, q.y);
    }
    o[9] = o[10] = o[11] = 0;
    uint4* dst = (uint4*)(eaa + (size_t)p * 12);
    dst[0] = *(uint4*)&o[0];
    dst[1] = *(uint4*)&o[4];
    dst[2] = *(uint4*)&o[8];
}

// ---------- self-loop edge attr = mean of incoming ea; append virtual edges ----------
__global__ void __launch_bounds__(256)
k_loop2(const int* __restrict__ rowptr, uint32_t* __restrict__ eaa,
        int* __restrict__ csr_src, int* __restrict__ csr_dst) {
    const int lane = threadIdx.x & 63;
    int wid = blockIdx.x * (blockDim.x >> 6) + (threadIdx.x >> 6);
    int nw = gridDim.x * (blockDim.x >> 6);

    for (int i = wid; i < NN; i += nw) {
        int beg = __builtin_amdgcn_readfirstlane(rowptr[i]);
        int end = __builtin_amdgcn_readfirstlane(rowptr[i + 1]);
        float s[18];
#pragma unroll
        for (int j = 0; j < 18; j++) s[j] = 0.f;
        for (int cs = beg; cs < end; cs += 64) {
            int cnt = end - cs; if (cnt > 64) cnt = 64;
            if (lane < cnt) {
                const uint32_t* pe = eaa + (size_t)(cs + lane) * 12;
                uint4 a = *(const uint4*)pe;
                uint4 b = *(const uint4*)(pe + 4);
                uint32_t c = pe[8];
                uint32_t w[9] = {a.x, a.y, a.z, a.w, b.x, b.y, b.z, b.w, c};
#pragma unroll
                for (int kk = 0; kk < 9; kk++) {
                    float2 q = uph(w[kk]);
                    s[2 * kk] += q.x; s[2 * kk + 1] += q.y;
                }
            }
        }
#pragma unroll
        for (int j = 0; j < 18; j++) {
#pragma unroll
            for (int off = 32; off; off >>= 1) s[j] += __shfl_xor(s[j], off, 64);
        }
        if (lane == 0) {
            int deg = end - beg;
            float rd = (deg > 0) ? 1.0f / (float)deg : 0.0f;
            uint32_t o[12];
#pragma unroll
            for (int kk = 0; kk < 9; kk++) o[kk] = packh2(s[2 * kk] * rd, s[2 * kk + 1] * rd);
            o[9] = o[10] = o[11] = 0;
            uint4* dst = (uint4*)(eaa + (size_t)(EE + i) * 12);
            dst[0] = *(uint4*)&o[0];
            dst[1] = *(uint4*)&o[4];
            dst[2] = *(uint4*)&o[8];
            csr_src[EE + i] = i; csr_dst[EE + i] = i;
        }
    }
}

// ---------- pack WeT (zero-padded to CP cols): per col: 9 fp16-pair dwords + att ----------
__global__ void k_pack_wet(const float* __restrict__ We, const float* __restrict__ att,
                           uint32_t* __restrict__ WeT, int C, int CP) {
    int t = blockIdx.x * blockDim.x + threadIdx.x;
    if (t >= CP * 10) return;
    int c = t / 10, kk = t - c * 10;
    int g = c >> 2, j = c & 3;
    uint32_t v = 0;
    if (c < C) {
        if (kk < 9) v = packh2(We[(2 * kk) * C + c], We[(2 * kk + 1) * C + c]);
        else v = __float_as_uint(att[c]);
    }
    WeT[g * 40 + j * 10 + kk] = v;
}

// ---------- combine Wl|Wr into padded Wc [K x NP], biases into bc [NP] ----------
__global__ void k_combine_w(const float* __restrict__ Wl, const float* __restrict__ bl,
                            const float* __restrict__ Wr, const float* __restrict__ br,
                            float* __restrict__ Wc, float* __restrict__ bc,
                            int K, int C, int NP) {
    int t = blockIdx.x * blockDim.x + threadIdx.x;
    if (t < K * NP) {
        int k = t / NP, n = t - k * NP;
        float v = 0.0f;
        if (n < C) v = Wl[k * C + n];
        else if (n < 2 * C) v = Wr[k * C + n - C];
        Wc[t] = v;
    }
    if (t < NP) {
        float v = 0.0f;
        if (t < C) v = bl[t];
        else if (t < 2 * C) v = br[t - C];
        bc[t] = v;
    }
}

// ---------- tiled dual GEMM -> xl16/xr16 (packed fp16, padded pitch RL) ----------
template <int KK, int NP, int C, int RL>
__global__ void __launch_bounds__(256)
k_gemm_dual(const float* __restrict__ A, const float* __restrict__ Wc,
            const float* __restrict__ bc,
            uint32_t* __restrict__ xl16, uint32_t* __restrict__ xr16) {
    constexpr int BM = 64, BN = 64, BK = 16;
    __shared__ float As[BK][BM];
    __shared__ float Ws[BK][BN];
    const int tidx = threadIdx.x;
    const int tx = tidx & 15;
    const int ty = tidx >> 4;
    const int m0 = blockIdx.x * BM;
    const int n0 = blockIdx.y * BN;

    float acc[4][4];
#pragma unroll
    for (int i2 = 0; i2 < 4; i2++)
#pragma unroll
        for (int j2 = 0; j2 < 4; j2++) acc[i2][j2] = 0.0f;

    for (int k0 = 0; k0 < KK; k0 += BK) {
        {
            int m = tidx >> 2;
            int kq = (tidx & 3) * 4;
            float4 v = make_float4(0.f, 0.f, 0.f, 0.f);
            if (m0 + m < NN && k0 + kq < KK)
                v = *(const float4*)(A + (size_t)(m0 + m) * KK + k0 + kq);
            As[kq + 0][m] = v.x; As[kq + 1][m] = v.y;
            As[kq + 2][m] = v.z; As[kq + 3][m] = v.w;
        }
        {
            int k = tidx >> 4;
            int nq = (tidx & 15) * 4;
            float4 v = make_float4(0.f, 0.f, 0.f, 0.f);
            if (k0 + k < KK)
                v = *(const float4*)(Wc + (size_t)(k0 + k) * NP + n0 + nq);
            *(float4*)&Ws[k][nq] = v;
        }
        __syncthreads();
#pragma unroll
        for (int k = 0; k < BK; k++) {
            float a[4], b[4];
            *(float4*)a = *(const float4*)&As[k][ty * 4];
            *(float4*)b = *(const float4*)&Ws[k][tx * 4];
#pragma unroll
            for (int i2 = 0; i2 < 4; i2++)
#pragma unroll
                for (int j2 = 0; j2 < 4; j2++) acc[i2][j2] += a[i2] * b[j2];
        }
        __syncthreads();
    }

    const int n = n0 + tx * 4;
    float4 bcv = *(const float4*)(bc + n);
#pragma unroll
    for (int i2 = 0; i2 < 4; i2++) {
        int m = m0 + ty * 4 + i2;
        if (m >= NN) continue;
        float4 o = make_float4(acc[i2][0] + bcv.x, acc[i2][1] + bcv.y,
                               acc[i2][2] + bcv.z, acc[i2][3] + bcv.w);
        uint2 p;
        p.x = packh2(o.x, o.y);
        p.y = packh2(o.z, o.w);
        if (n < C)          *(uint2*)(xl16 + (size_t)m * RL + n / 2) = p;
        else if (n < 2 * C) *(uint2*)(xr16 + (size_t)m * RL + (n - C) / 2) = p;
    }
}

// ---------- edge-parallel scores: full fp16 rows preloaded (R3 structure) ----------
// + split fdot2 chains (two independent accumulators per column) for ILP.
template <int C>
__global__ void __launch_bounds__(256, 2)
k_score(const int* __restrict__ csr_src, const int* __restrict__ csr_dst,
        const uint32_t* __restrict__ eaa, const uint32_t* __restrict__ WeT,
        const uint32_t* __restrict__ xl16, const uint32_t* __restrict__ xr16,
        float* __restrict__ scores) {
    constexpr int RL = ((C / 2) + 3) & ~3;   // padded dwords per row
    int pos = blockIdx.x * blockDim.x + threadIdx.x;
    if (pos >= ET) return;
    int s = csr_src[pos];
    int d = csr_dst[pos];

    // issue ALL loads (row src, row dst, edge attr) before any compute
    uint32_t lw[RL], rw[RL];
    const uint4* pl = (const uint4*)(xl16 + (size_t)s * RL);
    const uint4* pr = (const uint4*)(xr16 + (size_t)d * RL);
#pragma unroll
    for (int i = 0; i < RL / 4; i++) *(uint4*)&lw[4 * i] = pl[i];
#pragma unroll
    for (int i = 0; i < RL / 4; i++) *(uint4*)&rw[4 * i] = pr[i];
    const uint32_t* pe = eaa + (size_t)pos * 12;
    uint4 e0 = *(const uint4*)pe;
    uint4 e1 = *(const uint4*)(pe + 4);
    uint32_t e8 = pe[8];
    __builtin_amdgcn_sched_barrier(0);   // pin: loads issued before compute

    uint32_t ean[9] = {e0.x, e0.y, e0.z, e0.w, e1.x, e1.y, e1.z, e1.w, e8};

    float score = 0.0f;
#pragma unroll
    for (int g = 0; g < RL / 2; g++) {   // 2 dwords (4 cols) per group
        const uint32_t* wg = WeT + g * 40;   // wave-uniform -> scalar loads
        uint32_t u0 = pkadd(lw[2 * g], rw[2 * g]);       // v_pk_add_f16
        uint32_t u1 = pkadd(lw[2 * g + 1], rw[2 * g + 1]);
        float2 f0 = uph(u0), f1 = uph(u1);
        float lv[4] = {f0.x, f0.y, f1.x, f1.y};
#pragma unroll
        for (int j = 0; j < 4; j++) {
            // split 9-chain into 5 + 4 independent chains
            float wa = 0.0f, wb = 0.0f;
            wa = fdot2u(ean[0], wg[j * 10 + 0], wa);
            wa = fdot2u(ean[1], wg[j * 10 + 1], wa);
            wa = fdot2u(ean[2], wg[j * 10 + 2], wa);
            wa = fdot2u(ean[3], wg[j * 10 + 3], wa);
            wa = fdot2u(ean[4], wg[j * 10 + 4], wa);
            wb = fdot2u(ean[5], wg[j * 10 + 5], wb);
            wb = fdot2u(ean[6], wg[j * 10 + 6], wb);
            wb = fdot2u(ean[7], wg[j * 10 + 7], wb);
            wb = fdot2u(ean[8], wg[j * 10 + 8], wb);
            float u = lv[j] + wa + wb;
            float h = fmaxf(u, NEG_SLOPE * u);
            score = fmaf(__uint_as_float(wg[j * 10 + 9]), h, score);
        }
    }
    scores[pos] = score;
}

// ---------- per-node exact softmax + aggregation from fp16 rows (R3 structure) ------
template <int C, int VEC, int RELU>
__global__ void __launch_bounds__(256)
k_fin(const int* __restrict__ rowptr, const int* __restrict__ csr_src,
      const float* __restrict__ scores, const uint32_t* __restrict__ xl16,
      const float* __restrict__ bias, float* __restrict__ out) {
    constexpr int DW = VEC / 2;              // dwords per lane per row
    constexpr int RL = ((C / 2) + 3) & ~3;   // row pitch in dwords
    constexpr int NL = C / VEC;
    const int lane = threadIdx.x & 63;
    int wid = blockIdx.x * (blockDim.x >> 6) + (threadIdx.x >> 6);
    int nw = gridDim.x * (blockDim.x >> 6);
    const bool act = lane < NL;

    float bv[VEC];
    if (act) {
#pragma unroll
        for (int j = 0; j < VEC; j++) bv[j] = bias[lane * VEC + j];
    } else {
#pragma unroll
        for (int j = 0; j < VEC; j++) bv[j] = 0.f;
    }

    auto ldrow = [&](uint32_t (&buf)[DW], int node) {
        if (act) {
            if constexpr (DW == 2) {
                uint2 v = *(const uint2*)(xl16 + (size_t)node * RL + lane * 2);
                buf[0] = v.x; buf[1] = v.y;
            } else {
                buf[0] = xl16[(size_t)node * RL + lane];
            }
        } else {
#pragma unroll
            for (int q = 0; q < DW; q++) buf[q] = 0;
        }
    };

    for (int i = wid; i < NN; i += nw) {
        int beg = __builtin_amdgcn_readfirstlane(rowptr[i]);
        int end = __builtin_amdgcn_readfirstlane(rowptr[i + 1]);
        float s_self = scores[EE + i];

        // pass 1: exact max
        float m = s_self;
        for (int cs = beg; cs < end; cs += 64) {
            int cnt = end - cs; if (cnt > 64) cnt = 64;
            float sc = (lane < cnt) ? scores[cs + lane] : -INFINITY;
#pragma unroll
            for (int off = 32; off; off >>= 1) sc = fmaxf(sc, __shfl_xor(sc, off, 64));
            m = fmaxf(m, sc);
        }

        // self-loop contribution
        float acc[VEC];
        float pes = __expf(s_self - m);
        float z = pes;
        {
            uint32_t w[DW];
            ldrow(w, i);
#pragma unroll
            for (int q = 0; q < DW; q++) {
                float2 f = uph(w[q]);
                acc[2 * q] = pes * f.x;
                acc[2 * q + 1] = pes * f.y;
            }
        }

        // pass 2: exp + denom + aggregation (8-deep prefetch, pinned)
        for (int cs = beg; cs < end; cs += 64) {
            int cnt = end - cs; if (cnt > 64) cnt = 64;
            float sc = (lane < cnt) ? scores[cs + lane] : -INFINITY;
            int srcl = (lane < cnt) ? csr_src[cs + lane] : 0;
            float pe = __expf(sc - m);
            float zc = pe;
#pragma unroll
            for (int off = 32; off; off >>= 1) zc += __shfl_xor(zc, off, 64);
            z += zc;

            uint32_t A[4][DW], Bv[4][DW];
            auto LD4 = [&](uint32_t (&buf)[4][DW], int t0) {
#pragma unroll
                for (int q = 0; q < 4; q++) {
                    int t = t0 + q;
                    if (t < cnt) {
                        int sx = __builtin_amdgcn_readlane(srcl, t);
                        ldrow(buf[q], sx);
                    }
                }
            };
            auto USE4 = [&](uint32_t (&buf)[4][DW], int t0) {
#pragma unroll
                for (int q = 0; q < 4; q++) {
                    int t = t0 + q;
                    if (t < cnt) {
                        float a = rlanef(pe, t);
#pragma unroll
                        for (int qq = 0; qq < DW; qq++) {
                            float2 f = uph(buf[q][qq]);
                            acc[2 * qq] = fmaf(a, f.x, acc[2 * qq]);
                            acc[2 * qq + 1] = fmaf(a, f.y, acc[2 * qq + 1]);
                        }
                    }
                }
            };
            LD4(A, 0);
            for (int t0 = 0; t0 < cnt; t0 += 8) {
                if (t0 + 4 < cnt) LD4(Bv, t0 + 4);
                __builtin_amdgcn_sched_barrier(0);
                USE4(A, t0);
                if (t0 + 8 < cnt) LD4(A, t0 + 8);
                __builtin_amdgcn_sched_barrier(0);
                USE4(Bv, t0 + 4);
            }
        }

        float rz = 1.0f / z;
        if (act) {
            float o[VEC];
#pragma unroll
            for (int j = 0; j < VEC; j++) {
                o[j] = acc[j] * rz + bv[j];
                if (RELU) o[j] = fmaxf(o[j], 0.0f);
            }
            if constexpr (VEC == 4) {
                *(float4*)(out + (size_t)i * C + lane * 4) = make_float4(o[0], o[1], o[2], o[3]);
            } else {
                *(float2*)(out + (size_t)i * C + lane * 2) = make_float2(o[0], o[1]);
            }
        }
    }
}

// ---------- mean pooling per graph (batch_ids sorted); relu folded in ----------
__global__ void k_pool(const float* __restrict__ h, const int* __restrict__ batch,
                       float* __restrict__ pooled) {
    int g = blockIdx.x;
    int lo = 0, hi = NN;
    while (lo < hi) { int mid = (lo + hi) >> 1; if (batch[mid] < g) lo = mid + 1; else hi = mid; }
    int start = lo;
    lo = start; hi = NN;
    while (lo < hi) { int mid = (lo + hi) >> 1; if (batch[mid] < g + 1) lo = mid + 1; else hi = mid; }
    int end = lo;
    float cnt = (float)(end - start);
    int c = threadIdx.x;
    if (c < 200) {
        float acc = 0.0f;
        for (int i = start; i < end; i++) acc += fmaxf(h[(size_t)i * 200 + c], 0.0f);
        pooled[g * 200 + c] = acc / fmaxf(cnt, 1.0f);
    }
}

// ---------- small dense layers on [G, *] ----------
__global__ void k_mlp(const float* __restrict__ X, const float* __restrict__ W,
                      const float* __restrict__ b, float* __restrict__ Y,
                      int Cin, int Cout, int do_relu) {
    int t = blockIdx.x * blockDim.x + threadIdx.x;
    if (t >= GG * Cout) return;
    int g = t / Cout, j = t - g * Cout;
    const float* xrow = X + (size_t)g * Cin;
    float acc = b[j];
    for (int k = 0; k < Cin; k++) acc += xrow[k] * W[k * Cout + j];
    if (do_relu) acc = fmaxf(acc, 0.0f);
    Y[t] = acc;
}

extern "C" void kernel_launch(void* const* d_in, const int* in_sizes, int n_in,
                              void* d_out, int out_size, void* d_ws, size_t ws_size,
                              hipStream_t stream) {
    const float* x   = (const float*)d_in[0];
    const int*   ei  = (const int*)d_in[1];
    const float* ea  = (const float*)d_in[2];
    const int*   bat = (const int*)d_in[3];
    const float* W1l = (const float*)d_in[4];  const float* b1l = (const float*)d_in[5];
    const float* W1r = (const float*)d_in[6];  const float* b1r = (const float*)d_in[7];
    const float* W1e = (const float*)d_in[8];
    const float* a1  = (const float*)d_in[9];  const float* c1  = (const float*)d_in[10];
    const float* W2l = (const float*)d_in[11]; const float* b2l = (const float*)d_in[12];
    const float* W2r = (const float*)d_in[13]; const float* b2r = (const float*)d_in[14];
    const float* W2e = (const float*)d_in[15];
    const float* a2  = (const float*)d_in[16]; const float* c2  = (const float*)d_in[17];
    const float* W3  = (const float*)d_in[18]; const float* b3  = (const float*)d_in[19];
    const float* F1  = (const float*)d_in[20]; const float* bf1 = (const float*)d_in[21];
    const float* F2  = (const float*)d_in[22]; const float* bf2 = (const float*)d_in[23];
    const float* F3  = (const float*)d_in[24]; const float* bf3 = (const float*)d_in[25];

    const int* srcv = ei;        // edge_index[0]
    const int* dstv = ei + EE;   // edge_index[1]

    float* W = (float*)d_ws;
    size_t off = 0;
    int*      hist    = (int*)(W + off); off += NN;
    float*    h1      = W + off; off += (size_t)NN * 100;
    float*    h2      = W + off; off += (size_t)NN * 200;
    int*      rowptr  = (int*)(W + off); off += NN + 4;
    int*      cursor  = (int*)(W + off); off += NN;
    int*      bsum    = (int*)(W + off); off += 256;
    float*    scores  = W + off; off += ET;
    int*      csr_src = (int*)(W + off); off += ET;
    int*      csr_dst = (int*)(W + off); off += ET;
    uint32_t* eaa     = (uint32_t*)(W + off); off += (size_t)ET * 12;
    uint32_t* xl16    = (uint32_t*)(W + off); off += (size_t)NN * 100;
    uint32_t* xr16    = (uint32_t*)(W + off); off += (size_t)NN * 100;
    uint32_t* WeT1    = (uint32_t*)(W + off); off += 26 * 40;
    uint32_t* WeT2    = (uint32_t*)(W + off); off += 50 * 40;
    float*    Wc1     = W + off; off += 16 * 256;
    float*    bc1     = W + off; off += 256;
    float*    Wc2     = W + off; off += 100 * 448;
    float*    bc2     = W + off; off += 448;
    float*    pooled  = W + off; off += (size_t)GG * 200;
    float*    p400    = W + off; off += (size_t)GG * 400;
    float*    y1      = W + off; off += (size_t)GG * 200;
    float*    y2      = W + off; off += (size_t)GG * 100;
    (void)ws_size; (void)n_in; (void)in_sizes; (void)out_size;

    const int B = 256;
    const int NODEB = 12500;   // 50000 waves, 1 node each

    // ---- degree histogram + CSR by dst; scatter also packs ea + src/dst ----
    hipMemsetAsync(hist, 0, (size_t)NN * sizeof(int), stream);
    k_hist<<<(EE + B - 1) / B, B, 0, stream>>>(dstv, hist);
    k_scan_a<<<NB, 256, 0, stream>>>(hist, bsum);
    k_scan_b<<<1, 256, 0, stream>>>(bsum, rowptr);
    k_scan_c<<<NB, 256, 0, stream>>>(hist, bsum, rowptr, cursor);
    k_scatter<<<(EE + B - 1) / B, B, 0, stream>>>(srcv, dstv, ea, cursor, csr_src, csr_dst, eaa);
    k_loop2<<<NODEB, B, 0, stream>>>(rowptr, eaa, csr_src, csr_dst);

    // ---- weight prep ----
    k_pack_wet<<<(104 * 10 + B - 1) / B, B, 0, stream>>>(W1e, a1, WeT1, 100, 104);
    k_pack_wet<<<(200 * 10 + B - 1) / B, B, 0, stream>>>(W2e, a2, WeT2, 200, 200);
    k_combine_w<<<(16 * 256 + B - 1) / B, B, 0, stream>>>(W1l, b1l, W1r, b1r, Wc1, bc1, 16, 100, 256);
    k_combine_w<<<(100 * 448 + B - 1) / B, B, 0, stream>>>(W2l, b2l, W2r, b2r, Wc2, bc2, 100, 200, 448);

    // ---- GAT layer 1: 16 -> 100 (RL = 52; pad dwords must be zero) ----
    hipMemsetAsync(xl16, 0, (size_t)NN * 52 * 4, stream);
    hipMemsetAsync(xr16, 0, (size_t)NN * 52 * 4, stream);
    {
        dim3 grid((NN + 63) / 64, 256 / 64);
        k_gemm_dual<16, 256, 100, 52><<<grid, 256, 0, stream>>>(x, Wc1, bc1, xl16, xr16);
    }
    k_score<100><<<(ET + B - 1) / B, B, 0, stream>>>(csr_src, csr_dst, eaa, WeT1, xl16, xr16, scores);
    k_fin<100, 2, 1><<<NODEB, B, 0, stream>>>(rowptr, csr_src, scores, xl16, c1, h1);

    // ---- GAT layer 2: 100 -> 200 (RL = 100) ----
    {
        dim3 grid((NN + 63) / 64, 448 / 64);
        k_gemm_dual<100, 448, 200, 100><<<grid, 256, 0, stream>>>(h1, Wc2, bc2, xl16, xr16);
    }
    k_score<200><<<(ET + B - 1) / B, B, 0, stream>>>(csr_src, csr_dst, eaa, WeT2, xl16, xr16, scores);
    k_fin<200, 4, 0><<<NODEB, B, 0, stream>>>(rowptr, csr_src, scores, xl16, c2, h2);

    // ---- pool (mean over graph, relu fused) then W3 + FFN ----
    k_pool<<<GG, 256, 0, stream>>>(h2, bat, pooled);
    k_mlp<<<(GG * 400 + B - 1) / B, B, 0, stream>>>(pooled, W3, b3, p400, 200, 400, 0);
    k_mlp<<<(GG * 200 + B - 1) / B, B, 0, stream>>>(p400, F1, bf1, y1, 400, 200, 1);
    k_mlp<<<(GG * 100 + B - 1) / B, B, 0, stream>>>(y1, F2, bf2, y2, 200, 100, 1);
    k_mlp<<<(GG * 100 + B - 1) / B, B, 0, stream>>>(y2, F3, bf3, (float*)d_out, 100, 100, 0);
}

// Round 9
// 1412.160 us; speedup vs baseline: 1.2041x; 1.0000x over previous
//
#include <hip/hip_runtime.h>
#include <cstdint>
#include <climits>
#include <math.h>

#define NN 50000
#define EE 1600000
#define ET (EE + NN)   // real edges + one self-loop per node
#define GG 512
#define NEG_SLOPE 0.2f
#define NB 196          // ceil(NN/256) scan blocks

typedef _Float16 half2v __attribute__((ext_vector_type(2)));

__device__ __forceinline__ uint32_t packh2(float a, float b) {
    union { half2v h; uint32_t u; } c;
    c.h = half2v{(_Float16)a, (_Float16)b};
    return c.u;
}
__device__ __forceinline__ float2 uph(uint32_t u) {
    union { uint32_t u; half2v h; } c;
    c.u = u;
    return make_float2((float)c.h.x, (float)c.h.y);
}
__device__ __forceinline__ uint32_t pkadd(uint32_t a, uint32_t b) {
    union { uint32_t u; half2v h; } x, y, z;
    x.u = a; y.u = b;
    z.h = x.h + y.h;    // v_pk_add_f16
    return z.u;
}
__device__ __forceinline__ float fdot2u(uint32_t a, uint32_t b, float c) {
    union { uint32_t u; half2v h; } ua, ub;
    ua.u = a; ub.u = b;
    return __builtin_amdgcn_fdot2(ua.h, ub.h, c, false);
}
__device__ __forceinline__ float rlanef(float v, int l) {
    return __int_as_float(__builtin_amdgcn_readlane(__float_as_int(v), l));
}

// ---------- degree histogram ----------
__global__ void k_hist(const int* __restrict__ dst, int* __restrict__ hist) {
    int e = blockIdx.x * blockDim.x + threadIdx.x;
    if (e < EE) atomicAdd(&hist[dst[e]], 1);
}

// ---------- CSR build ----------
__global__ void k_scan_a(const int* __restrict__ hist, int* __restrict__ bsum) {
    __shared__ int tmp[256];
    int i = blockIdx.x * 256 + threadIdx.x;
    tmp[threadIdx.x] = (i < NN) ? hist[i] : 0;
    __syncthreads();
    for (int d = 128; d; d >>= 1) {
        if (threadIdx.x < d) tmp[threadIdx.x] += tmp[threadIdx.x + d];
        __syncthreads();
    }
    if (threadIdx.x == 0) bsum[blockIdx.x] = tmp[0];
}

__global__ void k_scan_b(int* __restrict__ bsum, int* __restrict__ rowptr) {
    __shared__ int tmp[256];
    int t = threadIdx.x;
    int v = (t < NB) ? bsum[t] : 0;
    tmp[t] = v;
    __syncthreads();
    for (int d = 1; d < 256; d <<= 1) {
        int u = (t >= d) ? tmp[t - d] : 0;
        __syncthreads();
        tmp[t] += u;
        __syncthreads();
    }
    if (t < NB) bsum[t] = tmp[t] - v;        // exclusive
    if (t == 255) rowptr[NN] = tmp[255];     // total == EE
}

// rowptr + cursor init fused
__global__ void k_scan_c(const int* __restrict__ hist, const int* __restrict__ bsum,
                         int* __restrict__ rowptr, int* __restrict__ cursor) {
    __shared__ int tmp[256];
    int i = blockIdx.x * 256 + threadIdx.x;
    int v = (i < NN) ? hist[i] : 0;
    tmp[threadIdx.x] = v;
    __syncthreads();
    for (int d = 1; d < 256; d <<= 1) {
        int t = (threadIdx.x >= d) ? tmp[threadIdx.x - d] : 0;
        __syncthreads();
        tmp[threadIdx.x] += t;
        __syncthreads();
    }
    if (i < NN) {
        int rp = tmp[threadIdx.x] - v + bsum[blockIdx.x];
        rowptr[i] = rp;
        cursor[i] = rp;
    }
}

// ---------- scatter + csr_src/csr_dst + fp16 AoS ea pack, one pass ----------
__global__ void k_scatter(const int* __restrict__ srcv, const int* __restrict__ dstv,
                          const float* __restrict__ ea, int* __restrict__ cursor,
                          int* __restrict__ csr_src, int* __restrict__ csr_dst,
                          uint32_t* __restrict__ eaa) {
    int e = blockIdx.x * blockDim.x + threadIdx.x;
    if (e >= EE) return;
    int d = dstv[e];
    int p = atomicAdd(&cursor[d], 1);
    csr_src[p] = srcv[e];
    csr_dst[p] = d;
    const float* r = ea + (size_t)e * 18;
    uint32_t o[12];
#pragma unroll
    for (int kk = 0; kk < 9; kk++) {
        float2 q = *(const float2*)(r + 2 * kk);
        o[kk] = packh2(q.x, q.y);
    }
    o[9] = o[10] = o[11] = 0;
    uint4* dst = (uint4*)(eaa + (size_t)p * 12);
    dst[0] = *(uint4*)&o[0];
    dst[1] = *(uint4*)&o[4];
    dst[2] = *(uint4*)&o[8];
}

// ---------- self-loop edge attr = mean of incoming ea; append virtual edges ----------
__global__ void __launch_bounds__(256)
k_loop2(const int* __restrict__ rowptr, uint32_t* __restrict__ eaa,
        int* __restrict__ csr_src, int* __restrict__ csr_dst) {
    const int lane = threadIdx.x & 63;
    int wid = blockIdx.x * (blockDim.x >> 6) + (threadIdx.x >> 6);
    int nw = gridDim.x * (blockDim.x >> 6);

    for (int i = wid; i < NN; i += nw) {
        int beg = __builtin_amdgcn_readfirstlane(rowptr[i]);
        int end = __builtin_amdgcn_readfirstlane(rowptr[i + 1]);
        float s[18];
#pragma unroll
        for (int j = 0; j < 18; j++) s[j] = 0.f;
        for (int cs = beg; cs < end; cs += 64) {
            int cnt = end - cs; if (cnt > 64) cnt = 64;
            if (lane < cnt) {
                const uint32_t* pe = eaa + (size_t)(cs + lane) * 12;
                uint4 a = *(const uint4*)pe;
                uint4 b = *(const uint4*)(pe + 4);
                uint32_t c = pe[8];
                uint32_t w[9] = {a.x, a.y, a.z, a.w, b.x, b.y, b.z, b.w, c};
#pragma unroll
                for (int kk = 0; kk < 9; kk++) {
                    float2 q = uph(w[kk]);
                    s[2 * kk] += q.x; s[2 * kk + 1] += q.y;
                }
            }
        }
#pragma unroll
        for (int j = 0; j < 18; j++) {
#pragma unroll
            for (int off = 32; off; off >>= 1) s[j] += __shfl_xor(s[j], off, 64);
        }
        if (lane == 0) {
            int deg = end - beg;
            float rd = (deg > 0) ? 1.0f / (float)deg : 0.0f;
            uint32_t o[12];
#pragma unroll
            for (int kk = 0; kk < 9; kk++) o[kk] = packh2(s[2 * kk] * rd, s[2 * kk + 1] * rd);
            o[9] = o[10] = o[11] = 0;
            uint4* dst = (uint4*)(eaa + (size_t)(EE + i) * 12);
            dst[0] = *(uint4*)&o[0];
            dst[1] = *(uint4*)&o[4];
            dst[2] = *(uint4*)&o[8];
            csr_src[EE + i] = i; csr_dst[EE + i] = i;
        }
    }
}

// ---------- pack WeT (zero-padded to CP cols): per col: 9 fp16-pair dwords + att ----------
__global__ void k_pack_wet(const float* __restrict__ We, const float* __restrict__ att,
                           uint32_t* __restrict__ WeT, int C, int CP) {
    int t = blockIdx.x * blockDim.x + threadIdx.x;
    if (t >= CP * 10) return;
    int c = t / 10, kk = t - c * 10;
    int g = c >> 2, j = c & 3;
    uint32_t v = 0;
    if (c < C) {
        if (kk < 9) v = packh2(We[(2 * kk) * C + c], We[(2 * kk + 1) * C + c]);
        else v = __float_as_uint(att[c]);
    }
    WeT[g * 40 + j * 10 + kk] = v;
}

// ---------- combine Wl|Wr into padded Wc [K x NP], biases into bc [NP] ----------
__global__ void k_combine_w(const float* __restrict__ Wl, const float* __restrict__ bl,
                            const float* __restrict__ Wr, const float* __restrict__ br,
                            float* __restrict__ Wc, float* __restrict__ bc,
                            int K, int C, int NP) {
    int t = blockIdx.x * blockDim.x + threadIdx.x;
    if (t < K * NP) {
        int k = t / NP, n = t - k * NP;
        float v = 0.0f;
        if (n < C) v = Wl[k * C + n];
        else if (n < 2 * C) v = Wr[k * C + n - C];
        Wc[t] = v;
    }
    if (t < NP) {
        float v = 0.0f;
        if (t < C) v = bl[t];
        else if (t < 2 * C) v = br[t - C];
        bc[t] = v;
    }
}

// ---------- tiled dual GEMM -> xl16/xr16 (packed fp16, padded pitch RL) ----------
template <int KK, int NP, int C, int RL>
__global__ void __launch_bounds__(256)
k_gemm_dual(const float* __restrict__ A, const float* __restrict__ Wc,
            const float* __restrict__ bc,
            uint32_t* __restrict__ xl16, uint32_t* __restrict__ xr16) {
    constexpr int BM = 64, BN = 64, BK = 16;
    __shared__ float As[BK][BM];
    __shared__ float Ws[BK][BN];
    const int tidx = threadIdx.x;
    const int tx = tidx & 15;
    const int ty = tidx >> 4;
    const int m0 = blockIdx.x * BM;
    const int n0 = blockIdx.y * BN;

    float acc[4][4];
#pragma unroll
    for (int i2 = 0; i2 < 4; i2++)
#pragma unroll
        for (int j2 = 0; j2 < 4; j2++) acc[i2][j2] = 0.0f;

    for (int k0 = 0; k0 < KK; k0 += BK) {
        {
            int m = tidx >> 2;
            int kq = (tidx & 3) * 4;
            float4 v = make_float4(0.f, 0.f, 0.f, 0.f);
            if (m0 + m < NN && k0 + kq < KK)
                v = *(const float4*)(A + (size_t)(m0 + m) * KK + k0 + kq);
            As[kq + 0][m] = v.x; As[kq + 1][m] = v.y;
            As[kq + 2][m] = v.z; As[kq + 3][m] = v.w;
        }
        {
            int k = tidx >> 4;
            int nq = (tidx & 15) * 4;
            float4 v = make_float4(0.f, 0.f, 0.f, 0.f);
            if (k0 + k < KK)
                v = *(const float4*)(Wc + (size_t)(k0 + k) * NP + n0 + nq);
            *(float4*)&Ws[k][nq] = v;
        }
        __syncthreads();
#pragma unroll
        for (int k = 0; k < BK; k++) {
            float a[4], b[4];
            *(float4*)a = *(const float4*)&As[k][ty * 4];
            *(float4*)b = *(const float4*)&Ws[k][tx * 4];
#pragma unroll
            for (int i2 = 0; i2 < 4; i2++)
#pragma unroll
                for (int j2 = 0; j2 < 4; j2++) acc[i2][j2] += a[i2] * b[j2];
        }
        __syncthreads();
    }

    const int n = n0 + tx * 4;
    float4 bcv = *(const float4*)(bc + n);
#pragma unroll
    for (int i2 = 0; i2 < 4; i2++) {
        int m = m0 + ty * 4 + i2;
        if (m >= NN) continue;
        float4 o = make_float4(acc[i2][0] + bcv.x, acc[i2][1] + bcv.y,
                               acc[i2][2] + bcv.z, acc[i2][3] + bcv.w);
        uint2 p;
        p.x = packh2(o.x, o.y);
        p.y = packh2(o.z, o.w);
        if (n < C)          *(uint2*)(xl16 + (size_t)m * RL + n / 2) = p;
        else if (n < 2 * C) *(uint2*)(xr16 + (size_t)m * RL + (n - C) / 2) = p;
    }
}

// ---------- edge-parallel scores: EPT edges/thread, full fp16 rows preloaded ----------
template <int C, int EPT>
__global__ void __launch_bounds__(256, 2)
k_score(const int* __restrict__ csr_src, const int* __restrict__ csr_dst,
        const uint32_t* __restrict__ eaa, const uint32_t* __restrict__ WeT,
        const uint32_t* __restrict__ xl16, const uint32_t* __restrict__ xr16,
        float* __restrict__ scores) {
    constexpr int RL = ((C / 2) + 3) & ~3;   // padded dwords per row
    int t = blockIdx.x * blockDim.x + threadIdx.x;
    int p0 = EPT * t;
    if (p0 >= ET) return;
    int pp[EPT];
    pp[0] = p0;
    if constexpr (EPT == 2) pp[1] = (p0 + 1 < ET) ? p0 + 1 : p0;

    // issue ALL loads (rows + edge attrs for all EPT edges) before any compute
    uint32_t lw[EPT][RL], rw[EPT][RL], ean[EPT][9];
#pragma unroll
    for (int e = 0; e < EPT; e++) {
        int s = csr_src[pp[e]];
        int d = csr_dst[pp[e]];
        const uint4* pl = (const uint4*)(xl16 + (size_t)s * RL);
        const uint4* pr = (const uint4*)(xr16 + (size_t)d * RL);
#pragma unroll
        for (int i = 0; i < RL / 4; i++) *(uint4*)&lw[e][4 * i] = pl[i];
#pragma unroll
        for (int i = 0; i < RL / 4; i++) *(uint4*)&rw[e][4 * i] = pr[i];
        const uint32_t* pe = eaa + (size_t)pp[e] * 12;
        uint4 e0 = *(const uint4*)pe;
        uint4 e1 = *(const uint4*)(pe + 4);
        ean[e][0] = e0.x; ean[e][1] = e0.y; ean[e][2] = e0.z; ean[e][3] = e0.w;
        ean[e][4] = e1.x; ean[e][5] = e1.y; ean[e][6] = e1.z; ean[e][7] = e1.w;
        ean[e][8] = pe[8];
    }
    __builtin_amdgcn_sched_barrier(0);   // pin: loads issued before compute

#pragma unroll
    for (int e = 0; e < EPT; e++) {
        float score = 0.0f;
#pragma unroll
        for (int g = 0; g < RL / 2; g++) {   // 2 dwords (4 cols) per group
            const uint32_t* wg = WeT + g * 40;   // wave-uniform -> scalar loads
            uint32_t u0 = pkadd(lw[e][2 * g], rw[e][2 * g]);
            uint32_t u1 = pkadd(lw[e][2 * g + 1], rw[e][2 * g + 1]);
            float2 f0 = uph(u0), f1 = uph(u1);
            float lv[4] = {f0.x, f0.y, f1.x, f1.y};
#pragma unroll
            for (int j = 0; j < 4; j++) {
                float w = 0.0f;
#pragma unroll
                for (int kk = 0; kk < 9; kk++) w = fdot2u(ean[e][kk], wg[j * 10 + kk], w);
                float u = lv[j] + w;
                float h = fmaxf(u, NEG_SLOPE * u);
                score = fmaf(__uint_as_float(wg[j * 10 + 9]), h, score);
            }
        }
        scores[pp[e]] = score;   // duplicate write (tail clamp) is benign
    }
}

// ---------- per-node exact softmax + aggregation from fp16 rows (R3 structure) ------
template <int C, int VEC, int RELU>
__global__ void __launch_bounds__(256)
k_fin(const int* __restrict__ rowptr, const int* __restrict__ csr_src,
      const float* __restrict__ scores, const uint32_t* __restrict__ xl16,
      const float* __restrict__ bias, float* __restrict__ out) {
    constexpr int DW = VEC / 2;              // dwords per lane per row
    constexpr int RL = ((C / 2) + 3) & ~3;   // row pitch in dwords
    constexpr int NL = C / VEC;
    const int lane = threadIdx.x & 63;
    int wid = blockIdx.x * (blockDim.x >> 6) + (threadIdx.x >> 6);
    int nw = gridDim.x * (blockDim.x >> 6);
    const bool act = lane < NL;

    float bv[VEC];
    if (act) {
#pragma unroll
        for (int j = 0; j < VEC; j++) bv[j] = bias[lane * VEC + j];
    } else {
#pragma unroll
        for (int j = 0; j < VEC; j++) bv[j] = 0.f;
    }

    auto ldrow = [&](uint32_t (&buf)[DW], int node) {
        if (act) {
            if constexpr (DW == 2) {
                uint2 v = *(const uint2*)(xl16 + (size_t)node * RL + lane * 2);
                buf[0] = v.x; buf[1] = v.y;
            } else {
                buf[0] = xl16[(size_t)node * RL + lane];
            }
        } else {
#pragma unroll
            for (int q = 0; q < DW; q++) buf[q] = 0;
        }
    };

    for (int i = wid; i < NN; i += nw) {
        int beg = __builtin_amdgcn_readfirstlane(rowptr[i]);
        int end = __builtin_amdgcn_readfirstlane(rowptr[i + 1]);
        float s_self = scores[EE + i];

        // pass 1: exact max
        float m = s_self;
        for (int cs = beg; cs < end; cs += 64) {
            int cnt = end - cs; if (cnt > 64) cnt = 64;
            float sc = (lane < cnt) ? scores[cs + lane] : -INFINITY;
#pragma unroll
            for (int off = 32; off; off >>= 1) sc = fmaxf(sc, __shfl_xor(sc, off, 64));
            m = fmaxf(m, sc);
        }

        // self-loop contribution
        float acc[VEC];
        float pes = __expf(s_self - m);
        float z = pes;
        {
            uint32_t w[DW];
            ldrow(w, i);
#pragma unroll
            for (int q = 0; q < DW; q++) {
                float2 f = uph(w[q]);
                acc[2 * q] = pes * f.x;
                acc[2 * q + 1] = pes * f.y;
            }
        }

        // pass 2: exp + denom + aggregation (8-deep prefetch, pinned)
        for (int cs = beg; cs < end; cs += 64) {
            int cnt = end - cs; if (cnt > 64) cnt = 64;
            float sc = (lane < cnt) ? scores[cs + lane] : -INFINITY;
            int srcl = (lane < cnt) ? csr_src[cs + lane] : 0;
            float pe = __expf(sc - m);
            float zc = pe;
#pragma unroll
            for (int off = 32; off; off >>= 1) zc += __shfl_xor(zc, off, 64);
            z += zc;

            uint32_t A[4][DW], Bv[4][DW];
            auto LD4 = [&](uint32_t (&buf)[4][DW], int t0) {
#pragma unroll
                for (int q = 0; q < 4; q++) {
                    int t = t0 + q;
                    if (t < cnt) {
                        int sx = __builtin_amdgcn_readlane(srcl, t);
                        ldrow(buf[q], sx);
                    }
                }
            };
            auto USE4 = [&](uint32_t (&buf)[4][DW], int t0) {
#pragma unroll
                for (int q = 0; q < 4; q++) {
                    int t = t0 + q;
                    if (t < cnt) {
                        float a = rlanef(pe, t);
#pragma unroll
                        for (int qq = 0; qq < DW; qq++) {
                            float2 f = uph(buf[q][qq]);
                            acc[2 * qq] = fmaf(a, f.x, acc[2 * qq]);
                            acc[2 * qq + 1] = fmaf(a, f.y, acc[2 * qq + 1]);
                        }
                    }
                }
            };
            LD4(A, 0);
            for (int t0 = 0; t0 < cnt; t0 += 8) {
                if (t0 + 4 < cnt) LD4(Bv, t0 + 4);
                __builtin_amdgcn_sched_barrier(0);
                USE4(A, t0);
                if (t0 + 8 < cnt) LD4(A, t0 + 8);
                __builtin_amdgcn_sched_barrier(0);
                USE4(Bv, t0 + 4);
            }
        }

        float rz = 1.0f / z;
        if (act) {
            float o[VEC];
#pragma unroll
            for (int j = 0; j < VEC; j++) {
                o[j] = acc[j] * rz + bv[j];
                if (RELU) o[j] = fmaxf(o[j], 0.0f);
            }
            if constexpr (VEC == 4) {
                *(float4*)(out + (size_t)i * C + lane * 4) = make_float4(o[0], o[1], o[2], o[3]);
            } else {
                *(float2*)(out + (size_t)i * C + lane * 2) = make_float2(o[0], o[1]);
            }
        }
    }
}

// ---------- mean pooling per graph (batch_ids sorted); relu folded in ----------
__global__ void k_pool(const float* __restrict__ h, const int* __restrict__ batch,
                       float* __restrict__ pooled) {
    int g = blockIdx.x;
    int lo = 0, hi = NN;
    while (lo < hi) { int mid = (lo + hi) >> 1; if (batch[mid] < g) lo = mid + 1; else hi = mid; }
    int start = lo;
    lo = start; hi = NN;
    while (lo < hi) { int mid = (lo + hi) >> 1; if (batch[mid] < g + 1) lo = mid + 1; else hi = mid; }
    int end = lo;
    float cnt = (float)(end - start);
    int c = threadIdx.x;
    if (c < 200) {
        float acc = 0.0f;
        for (int i = start; i < end; i++) acc += fmaxf(h[(size_t)i * 200 + c], 0.0f);
        pooled[g * 200 + c] = acc / fmaxf(cnt, 1.0f);
    }
}

// ---------- small dense layers on [G, *] ----------
__global__ void k_mlp(const float* __restrict__ X, const float* __restrict__ W,
                      const float* __restrict__ b, float* __restrict__ Y,
                      int Cin, int Cout, int do_relu) {
    int t = blockIdx.x * blockDim.x + threadIdx.x;
    if (t >= GG * Cout) return;
    int g = t / Cout, j = t - g * Cout;
    const float* xrow = X + (size_t)g * Cin;
    float acc = b[j];
    for (int k = 0; k < Cin; k++) acc += xrow[k] * W[k * Cout + j];
    if (do_relu) acc = fmaxf(acc, 0.0f);
    Y[t] = acc;
}

extern "C" void kernel_launch(void* const* d_in, const int* in_sizes, int n_in,
                              void* d_out, int out_size, void* d_ws, size_t ws_size,
                              hipStream_t stream) {
    const float* x   = (const float*)d_in[0];
    const int*   ei  = (const int*)d_in[1];
    const float* ea  = (const float*)d_in[2];
    const int*   bat = (const int*)d_in[3];
    const float* W1l = (const float*)d_in[4];  const float* b1l = (const float*)d_in[5];
    const float* W1r = (const float*)d_in[6];  const float* b1r = (const float*)d_in[7];
    const float* W1e = (const float*)d_in[8];
    const float* a1  = (const float*)d_in[9];  const float* c1  = (const float*)d_in[10];
    const float* W2l = (const float*)d_in[11]; const float* b2l = (const float*)d_in[12];
    const float* W2r = (const float*)d_in[13]; const float* b2r = (const float*)d_in[14];
    const float* W2e = (const float*)d_in[15];
    const float* a2  = (const float*)d_in[16]; const float* c2  = (const float*)d_in[17];
    const float* W3  = (const float*)d_in[18]; const float* b3  = (const float*)d_in[19];
    const float* F1  = (const float*)d_in[20]; const float* bf1 = (const float*)d_in[21];
    const float* F2  = (const float*)d_in[22]; const float* bf2 = (const float*)d_in[23];
    const float* F3  = (const float*)d_in[24]; const float* bf3 = (const float*)d_in[25];

    const int* srcv = ei;        // edge_index[0]
    const int* dstv = ei + EE;   // edge_index[1]

    float* W = (float*)d_ws;
    size_t off = 0;
    int*      hist    = (int*)(W + off); off += NN;
    float*    h1      = W + off; off += (size_t)NN * 100;
    float*    h2      = W + off; off += (size_t)NN * 200;
    int*      rowptr  = (int*)(W + off); off += NN + 4;
    int*      cursor  = (int*)(W + off); off += NN;
    int*      bsum    = (int*)(W + off); off += 256;
    float*    scores  = W + off; off += ET;
    int*      csr_src = (int*)(W + off); off += ET;
    int*      csr_dst = (int*)(W + off); off += ET;
    uint32_t* eaa     = (uint32_t*)(W + off); off += (size_t)ET * 12;
    uint32_t* xl16    = (uint32_t*)(W + off); off += (size_t)NN * 100;
    uint32_t* xr16    = (uint32_t*)(W + off); off += (size_t)NN * 100;
    uint32_t* WeT1    = (uint32_t*)(W + off); off += 26 * 40;
    uint32_t* WeT2    = (uint32_t*)(W + off); off += 50 * 40;
    float*    Wc1     = W + off; off += 16 * 256;
    float*    bc1     = W + off; off += 256;
    float*    Wc2     = W + off; off += 100 * 448;
    float*    bc2     = W + off; off += 448;
    float*    pooled  = W + off; off += (size_t)GG * 200;
    float*    p400    = W + off; off += (size_t)GG * 400;
    float*    y1      = W + off; off += (size_t)GG * 200;
    float*    y2      = W + off; off += (size_t)GG * 100;
    (void)ws_size; (void)n_in; (void)in_sizes; (void)out_size;

    const int B = 256;
    const int NODEB = 12500;   // 50000 waves, 1 node each

    // ---- degree histogram + CSR by dst; scatter also packs ea + src/dst ----
    hipMemsetAsync(hist, 0, (size_t)NN * sizeof(int), stream);
    k_hist<<<(EE + B - 1) / B, B, 0, stream>>>(dstv, hist);
    k_scan_a<<<NB, 256, 0, stream>>>(hist, bsum);
    k_scan_b<<<1, 256, 0, stream>>>(bsum, rowptr);
    k_scan_c<<<NB, 256, 0, stream>>>(hist, bsum, rowptr, cursor);
    k_scatter<<<(EE + B - 1) / B, B, 0, stream>>>(srcv, dstv, ea, cursor, csr_src, csr_dst, eaa);
    k_loop2<<<NODEB, B, 0, stream>>>(rowptr, eaa, csr_src, csr_dst);

    // ---- weight prep ----
    k_pack_wet<<<(104 * 10 + B - 1) / B, B, 0, stream>>>(W1e, a1, WeT1, 100, 104);
    k_pack_wet<<<(200 * 10 + B - 1) / B, B, 0, stream>>>(W2e, a2, WeT2, 200, 200);
    k_combine_w<<<(16 * 256 + B - 1) / B, B, 0, stream>>>(W1l, b1l, W1r, b1r, Wc1, bc1, 16, 100, 256);
    k_combine_w<<<(100 * 448 + B - 1) / B, B, 0, stream>>>(W2l, b2l, W2r, b2r, Wc2, bc2, 100, 200, 448);

    // ---- GAT layer 1: 16 -> 100 (RL = 52; pad dwords must be zero) ----
    hipMemsetAsync(xl16, 0, (size_t)NN * 52 * 4, stream);
    hipMemsetAsync(xr16, 0, (size_t)NN * 52 * 4, stream);
    {
        dim3 grid((NN + 63) / 64, 256 / 64);
        k_gemm_dual<16, 256, 100, 52><<<grid, 256, 0, stream>>>(x, Wc1, bc1, xl16, xr16);
    }
    k_score<100, 2><<<(ET / 2 + B) / B, B, 0, stream>>>(csr_src, csr_dst, eaa, WeT1, xl16, xr16, scores);
    k_fin<100, 2, 1><<<NODEB, B, 0, stream>>>(rowptr, csr_src, scores, xl16, c1, h1);

    // ---- GAT layer 2: 100 -> 200 (RL = 100) ----
    {
        dim3 grid((NN + 63) / 64, 448 / 64);
        k_gemm_dual<100, 448, 200, 100><<<grid, 256, 0, stream>>>(h1, Wc2, bc2, xl16, xr16);
    }
    k_score<200, 1><<<(ET + B - 1) / B, B, 0, stream>>>(csr_src, csr_dst, eaa, WeT2, xl16, xr16, scores);
    k_fin<200, 4, 0><<<NODEB, B, 0, stream>>>(rowptr, csr_src, scores, xl16, c2, h2);

    // ---- pool (mean over graph, relu fused) then W3 + FFN ----
    k_pool<<<GG, 256, 0, stream>>>(h2, bat, pooled);
    k_mlp<<<(GG * 400 + B - 1) / B, B, 0, stream>>>(pooled, W3, b3, p400, 200, 400, 0);
    k_mlp<<<(GG * 200 + B - 1) / B, B, 0, stream>>>(p400, F1, bf1, y1, 400, 200, 1);
    k_mlp<<<(GG * 100 + B - 1) / B, B, 0, stream>>>(y1, F2, bf2, y2, 200, 100, 1);
    k_mlp<<<(GG * 100 + B - 1) / B, B, 0, stream>>>(y2, F3, bf3, (float*)d_out, 100, 100, 0);
}

// Round 10
// 1358.418 us; speedup vs baseline: 1.2518x; 1.0396x over previous
//
#include <hip/hip_runtime.h>
#include <cstdint>
#include <climits>
#include <math.h>

#define NN 50000
#define EE 1600000
#define ET (EE + NN)   // real edges + one self-loop per node
#define GG 512
#define NEG_SLOPE 0.2f
#define NB 196          // ceil(NN/256) scan blocks

typedef _Float16 half2v __attribute__((ext_vector_type(2)));

__device__ __forceinline__ uint32_t packh2(float a, float b) {
    union { half2v h; uint32_t u; } c;
    c.h = half2v{(_Float16)a, (_Float16)b};
    return c.u;
}
__device__ __forceinline__ float2 uph(uint32_t u) {
    union { uint32_t u; half2v h; } c;
    c.u = u;
    return make_float2((float)c.h.x, (float)c.h.y);
}
__device__ __forceinline__ uint32_t pkadd(uint32_t a, uint32_t b) {
    union { uint32_t u; half2v h; } x, y, z;
    x.u = a; y.u = b;
    z.h = x.h + y.h;    // v_pk_add_f16
    return z.u;
}
__device__ __forceinline__ float fdot2u(uint32_t a, uint32_t b, float c) {
    union { uint32_t u; half2v h; } ua, ub;
    ua.u = a; ub.u = b;
    return __builtin_amdgcn_fdot2(ua.h, ub.h, c, false);
}
__device__ __forceinline__ float rlanef(float v, int l) {
    return __int_as_float(__builtin_amdgcn_readlane(__float_as_int(v), l));
}

// ---------- degree histogram ----------
__global__ void k_hist(const int* __restrict__ dst, int* __restrict__ hist) {
    int e = blockIdx.x * blockDim.x + threadIdx.x;
    if (e < EE) atomicAdd(&hist[dst[e]], 1);
}

// ---------- CSR build ----------
__global__ void k_scan_a(const int* __restrict__ hist, int* __restrict__ bsum) {
    __shared__ int tmp[256];
    int i = blockIdx.x * 256 + threadIdx.x;
    tmp[threadIdx.x] = (i < NN) ? hist[i] : 0;
    __syncthreads();
    for (int d = 128; d; d >>= 1) {
        if (threadIdx.x < d) tmp[threadIdx.x] += tmp[threadIdx.x + d];
        __syncthreads();
    }
    if (threadIdx.x == 0) bsum[blockIdx.x] = tmp[0];
}

__global__ void k_scan_b(int* __restrict__ bsum, int* __restrict__ rowptr) {
    __shared__ int tmp[256];
    int t = threadIdx.x;
    int v = (t < NB) ? bsum[t] : 0;
    tmp[t] = v;
    __syncthreads();
    for (int d = 1; d < 256; d <<= 1) {
        int u = (t >= d) ? tmp[t - d] : 0;
        __syncthreads();
        tmp[t] += u;
        __syncthreads();
    }
    if (t < NB) bsum[t] = tmp[t] - v;        // exclusive
    if (t == 255) rowptr[NN] = tmp[255];     // total == EE
}

// rowptr + cursor init fused
__global__ void k_scan_c(const int* __restrict__ hist, const int* __restrict__ bsum,
                         int* __restrict__ rowptr, int* __restrict__ cursor) {
    __shared__ int tmp[256];
    int i = blockIdx.x * 256 + threadIdx.x;
    int v = (i < NN) ? hist[i] : 0;
    tmp[threadIdx.x] = v;
    __syncthreads();
    for (int d = 1; d < 256; d <<= 1) {
        int t = (threadIdx.x >= d) ? tmp[threadIdx.x - d] : 0;
        __syncthreads();
        tmp[threadIdx.x] += t;
        __syncthreads();
    }
    if (i < NN) {
        int rp = tmp[threadIdx.x] - v + bsum[blockIdx.x];
        rowptr[i] = rp;
        cursor[i] = rp;
    }
}

// ---------- scatter + csr_src/csr_dst + fp16 AoS ea pack, one pass ----------
__global__ void k_scatter(const int* __restrict__ srcv, const int* __restrict__ dstv,
                          const float* __restrict__ ea, int* __restrict__ cursor,
                          int* __restrict__ csr_src, int* __restrict__ csr_dst,
                          uint32_t* __restrict__ eaa) {
    int e = blockIdx.x * blockDim.x + threadIdx.x;
    if (e >= EE) return;
    int d = dstv[e];
    int p = atomicAdd(&cursor[d], 1);
    csr_src[p] = srcv[e];
    csr_dst[p] = d;
    const float* r = ea + (size_t)e * 18;
    uint32_t o[12];
#pragma unroll
    for (int kk = 0; kk < 9; kk++) {
        float2 q = *(const float2*)(r + 2 * kk);
        o[kk] = packh2(q.x, q.y);
    }
    o[9] = o[10] = o[11] = 0;
    uint4* dst = (uint4*)(eaa + (size_t)p * 12);
    dst[0] = *(uint4*)&o[0];
    dst[1] = *(uint4*)&o[4];
    dst[2] = *(uint4*)&o[8];
}

// ---------- self-loop edge attr = mean of incoming ea; append virtual edges ----------
__global__ void __launch_bounds__(256)
k_loop2(const int* __restrict__ rowptr, uint32_t* __restrict__ eaa,
        int* __restrict__ csr_src, int* __restrict__ csr_dst) {
    const int lane = threadIdx.x & 63;
    int wid = blockIdx.x * (blockDim.x >> 6) + (threadIdx.x >> 6);
    int nw = gridDim.x * (blockDim.x >> 6);

    for (int i = wid; i < NN; i += nw) {
        int beg = __builtin_amdgcn_readfirstlane(rowptr[i]);
        int end = __builtin_amdgcn_readfirstlane(rowptr[i + 1]);
        float s[18];
#pragma unroll
        for (int j = 0; j < 18; j++) s[j] = 0.f;
        for (int cs = beg; cs < end; cs += 64) {
            int cnt = end - cs; if (cnt > 64) cnt = 64;
            if (lane < cnt) {
                const uint32_t* pe = eaa + (size_t)(cs + lane) * 12;
                uint4 a = *(const uint4*)pe;
                uint4 b = *(const uint4*)(pe + 4);
                uint32_t c = pe[8];
                uint32_t w[9] = {a.x, a.y, a.z, a.w, b.x, b.y, b.z, b.w, c};
#pragma unroll
                for (int kk = 0; kk < 9; kk++) {
                    float2 q = uph(w[kk]);
                    s[2 * kk] += q.x; s[2 * kk + 1] += q.y;
                }
            }
        }
#pragma unroll
        for (int j = 0; j < 18; j++) {
#pragma unroll
            for (int off = 32; off; off >>= 1) s[j] += __shfl_xor(s[j], off, 64);
        }
        if (lane == 0) {
            int deg = end - beg;
            float rd = (deg > 0) ? 1.0f / (float)deg : 0.0f;
            uint32_t o[12];
#pragma unroll
            for (int kk = 0; kk < 9; kk++) o[kk] = packh2(s[2 * kk] * rd, s[2 * kk + 1] * rd);
            o[9] = o[10] = o[11] = 0;
            uint4* dst = (uint4*)(eaa + (size_t)(EE + i) * 12);
            dst[0] = *(uint4*)&o[0];
            dst[1] = *(uint4*)&o[4];
            dst[2] = *(uint4*)&o[8];
            csr_src[EE + i] = i; csr_dst[EE + i] = i;
        }
    }
}

// ---------- pack WeT (zero-padded to CP cols): per col: 9 fp16-pair dwords + att ----------
__global__ void k_pack_wet(const float* __restrict__ We, const float* __restrict__ att,
                           uint32_t* __restrict__ WeT, int C, int CP) {
    int t = blockIdx.x * blockDim.x + threadIdx.x;
    if (t >= CP * 10) return;
    int c = t / 10, kk = t - c * 10;
    int g = c >> 2, j = c & 3;
    uint32_t v = 0;
    if (c < C) {
        if (kk < 9) v = packh2(We[(2 * kk) * C + c], We[(2 * kk + 1) * C + c]);
        else v = __float_as_uint(att[c]);
    }
    WeT[g * 40 + j * 10 + kk] = v;
}

// ---------- combine Wl|Wr into padded Wc [K x NP], biases into bc [NP] ----------
__global__ void k_combine_w(const float* __restrict__ Wl, const float* __restrict__ bl,
                            const float* __restrict__ Wr, const float* __restrict__ br,
                            float* __restrict__ Wc, float* __restrict__ bc,
                            int K, int C, int NP) {
    int t = blockIdx.x * blockDim.x + threadIdx.x;
    if (t < K * NP) {
        int k = t / NP, n = t - k * NP;
        float v = 0.0f;
        if (n < C) v = Wl[k * C + n];
        else if (n < 2 * C) v = Wr[k * C + n - C];
        Wc[t] = v;
    }
    if (t < NP) {
        float v = 0.0f;
        if (t < C) v = bl[t];
        else if (t < 2 * C) v = br[t - C];
        bc[t] = v;
    }
}

// ---------- tiled dual GEMM -> xl16/xr16 (packed fp16, padded pitch RL) ----------
template <int KK, int NP, int C, int RL>
__global__ void __launch_bounds__(256)
k_gemm_dual(const float* __restrict__ A, const float* __restrict__ Wc,
            const float* __restrict__ bc,
            uint32_t* __restrict__ xl16, uint32_t* __restrict__ xr16) {
    constexpr int BM = 64, BN = 64, BK = 16;
    __shared__ float As[BK][BM];
    __shared__ float Ws[BK][BN];
    const int tidx = threadIdx.x;
    const int tx = tidx & 15;
    const int ty = tidx >> 4;
    const int m0 = blockIdx.x * BM;
    const int n0 = blockIdx.y * BN;

    float acc[4][4];
#pragma unroll
    for (int i2 = 0; i2 < 4; i2++)
#pragma unroll
        for (int j2 = 0; j2 < 4; j2++) acc[i2][j2] = 0.0f;

    for (int k0 = 0; k0 < KK; k0 += BK) {
        {
            int m = tidx >> 2;
            int kq = (tidx & 3) * 4;
            float4 v = make_float4(0.f, 0.f, 0.f, 0.f);
            if (m0 + m < NN && k0 + kq < KK)
                v = *(const float4*)(A + (size_t)(m0 + m) * KK + k0 + kq);
            As[kq + 0][m] = v.x; As[kq + 1][m] = v.y;
            As[kq + 2][m] = v.z; As[kq + 3][m] = v.w;
        }
        {
            int k = tidx >> 4;
            int nq = (tidx & 15) * 4;
            float4 v = make_float4(0.f, 0.f, 0.f, 0.f);
            if (k0 + k < KK)
                v = *(const float4*)(Wc + (size_t)(k0 + k) * NP + n0 + nq);
            *(float4*)&Ws[k][nq] = v;
        }
        __syncthreads();
#pragma unroll
        for (int k = 0; k < BK; k++) {
            float a[4], b[4];
            *(float4*)a = *(const float4*)&As[k][ty * 4];
            *(float4*)b = *(const float4*)&Ws[k][tx * 4];
#pragma unroll
            for (int i2 = 0; i2 < 4; i2++)
#pragma unroll
                for (int j2 = 0; j2 < 4; j2++) acc[i2][j2] += a[i2] * b[j2];
        }
        __syncthreads();
    }

    const int n = n0 + tx * 4;
    float4 bcv = *(const float4*)(bc + n);
#pragma unroll
    for (int i2 = 0; i2 < 4; i2++) {
        int m = m0 + ty * 4 + i2;
        if (m >= NN) continue;
        float4 o = make_float4(acc[i2][0] + bcv.x, acc[i2][1] + bcv.y,
                               acc[i2][2] + bcv.z, acc[i2][3] + bcv.w);
        uint2 p;
        p.x = packh2(o.x, o.y);
        p.y = packh2(o.z, o.w);
        if (n < C)          *(uint2*)(xl16 + (size_t)m * RL + n / 2) = p;
        else if (n < 2 * C) *(uint2*)(xr16 + (size_t)m * RL + (n - C) / 2) = p;
    }
}

// ---------- edge-parallel scores, UNPINNED (R2 structure): compiler JIT-pipelines ----
// High-occupancy variant: VGPR stays low, ~6 waves/SIMD provide the MLP.
template <int C>
__global__ void __launch_bounds__(256)
k_score_np(const int* __restrict__ csr_src, const int* __restrict__ csr_dst,
           const uint32_t* __restrict__ eaa, const uint32_t* __restrict__ WeT,
           const uint32_t* __restrict__ xl16, const uint32_t* __restrict__ xr16,
           float* __restrict__ scores) {
    constexpr int RL = ((C / 2) + 3) & ~3;   // padded dwords per row
    int pos = blockIdx.x * blockDim.x + threadIdx.x;
    if (pos >= ET) return;
    int s = csr_src[pos];
    int d = csr_dst[pos];

    uint32_t lw[RL], rw[RL];
    const uint4* pl = (const uint4*)(xl16 + (size_t)s * RL);
    const uint4* pr = (const uint4*)(xr16 + (size_t)d * RL);
#pragma unroll
    for (int i = 0; i < RL / 4; i++) *(uint4*)&lw[4 * i] = pl[i];
#pragma unroll
    for (int i = 0; i < RL / 4; i++) *(uint4*)&rw[4 * i] = pr[i];
    const uint32_t* pe = eaa + (size_t)pos * 12;
    uint4 e0 = *(const uint4*)pe;
    uint4 e1 = *(const uint4*)(pe + 4);
    uint32_t e8 = pe[8];
    uint32_t ean[9] = {e0.x, e0.y, e0.z, e0.w, e1.x, e1.y, e1.z, e1.w, e8};

    float score = 0.0f;
#pragma unroll 2
    for (int g = 0; g < C / 4; g++) {        // only REAL columns (pads unread)
        const uint32_t* wg = WeT + g * 40;   // wave-uniform -> scalar loads
        uint32_t u0 = pkadd(lw[2 * g], rw[2 * g]);
        uint32_t u1 = pkadd(lw[2 * g + 1], rw[2 * g + 1]);
        float2 f0 = uph(u0), f1 = uph(u1);
        float lv[4] = {f0.x, f0.y, f1.x, f1.y};
#pragma unroll
        for (int j = 0; j < 4; j++) {
            float w = 0.0f;
#pragma unroll
            for (int kk = 0; kk < 9; kk++) w = fdot2u(ean[kk], wg[j * 10 + kk], w);
            float u = lv[j] + w;
            float h = fmaxf(u, NEG_SLOPE * u);
            score = fmaf(__uint_as_float(wg[j * 10 + 9]), h, score);
        }
    }
    scores[pos] = score;
}

// ---------- edge-parallel scores, PINNED preload (kept for C=200) ----------
template <int C>
__global__ void __launch_bounds__(256, 2)
k_score_p(const int* __restrict__ csr_src, const int* __restrict__ csr_dst,
          const uint32_t* __restrict__ eaa, const uint32_t* __restrict__ WeT,
          const uint32_t* __restrict__ xl16, const uint32_t* __restrict__ xr16,
          float* __restrict__ scores) {
    constexpr int RL = ((C / 2) + 3) & ~3;
    int pos = blockIdx.x * blockDim.x + threadIdx.x;
    if (pos >= ET) return;
    int s = csr_src[pos];
    int d = csr_dst[pos];

    uint32_t lw[RL], rw[RL];
    const uint4* pl = (const uint4*)(xl16 + (size_t)s * RL);
    const uint4* pr = (const uint4*)(xr16 + (size_t)d * RL);
#pragma unroll
    for (int i = 0; i < RL / 4; i++) *(uint4*)&lw[4 * i] = pl[i];
#pragma unroll
    for (int i = 0; i < RL / 4; i++) *(uint4*)&rw[4 * i] = pr[i];
    const uint32_t* pe = eaa + (size_t)pos * 12;
    uint4 e0 = *(const uint4*)pe;
    uint4 e1 = *(const uint4*)(pe + 4);
    uint32_t e8 = pe[8];
    __builtin_amdgcn_sched_barrier(0);   // pin: loads issued before compute

    uint32_t ean[9] = {e0.x, e0.y, e0.z, e0.w, e1.x, e1.y, e1.z, e1.w, e8};

    float score = 0.0f;
#pragma unroll
    for (int g = 0; g < C / 4; g++) {
        const uint32_t* wg = WeT + g * 40;
        uint32_t u0 = pkadd(lw[2 * g], rw[2 * g]);
        uint32_t u1 = pkadd(lw[2 * g + 1], rw[2 * g + 1]);
        float2 f0 = uph(u0), f1 = uph(u1);
        float lv[4] = {f0.x, f0.y, f1.x, f1.y};
#pragma unroll
        for (int j = 0; j < 4; j++) {
            float w = 0.0f;
#pragma unroll
            for (int kk = 0; kk < 9; kk++) w = fdot2u(ean[kk], wg[j * 10 + kk], w);
            float u = lv[j] + w;
            float h = fmaxf(u, NEG_SLOPE * u);
            score = fmaf(__uint_as_float(wg[j * 10 + 9]), h, score);
        }
    }
    scores[pos] = score;
}

// ---------- per-node exact softmax + aggregation from fp16 rows (R3 structure) ------
template <int C, int VEC, int RELU>
__global__ void __launch_bounds__(256)
k_fin(const int* __restrict__ rowptr, const int* __restrict__ csr_src,
      const float* __restrict__ scores, const uint32_t* __restrict__ xl16,
      const float* __restrict__ bias, float* __restrict__ out) {
    constexpr int DW = VEC / 2;              // dwords per lane per row
    constexpr int RL = ((C / 2) + 3) & ~3;   // row pitch in dwords
    constexpr int NL = C / VEC;
    const int lane = threadIdx.x & 63;
    int wid = blockIdx.x * (blockDim.x >> 6) + (threadIdx.x >> 6);
    int nw = gridDim.x * (blockDim.x >> 6);
    const bool act = lane < NL;

    float bv[VEC];
    if (act) {
#pragma unroll
        for (int j = 0; j < VEC; j++) bv[j] = bias[lane * VEC + j];
    } else {
#pragma unroll
        for (int j = 0; j < VEC; j++) bv[j] = 0.f;
    }

    auto ldrow = [&](uint32_t (&buf)[DW], int node) {
        if (act) {
            if constexpr (DW == 2) {
                uint2 v = *(const uint2*)(xl16 + (size_t)node * RL + lane * 2);
                buf[0] = v.x; buf[1] = v.y;
            } else {
                buf[0] = xl16[(size_t)node * RL + lane];
            }
        } else {
#pragma unroll
            for (int q = 0; q < DW; q++) buf[q] = 0;
        }
    };

    for (int i = wid; i < NN; i += nw) {
        int beg = __builtin_amdgcn_readfirstlane(rowptr[i]);
        int end = __builtin_amdgcn_readfirstlane(rowptr[i + 1]);
        float s_self = scores[EE + i];

        // pass 1: exact max
        float m = s_self;
        for (int cs = beg; cs < end; cs += 64) {
            int cnt = end - cs; if (cnt > 64) cnt = 64;
            float sc = (lane < cnt) ? scores[cs + lane] : -INFINITY;
#pragma unroll
            for (int off = 32; off; off >>= 1) sc = fmaxf(sc, __shfl_xor(sc, off, 64));
            m = fmaxf(m, sc);
        }

        // self-loop contribution
        float acc[VEC];
        float pes = __expf(s_self - m);
        float z = pes;
        {
            uint32_t w[DW];
            ldrow(w, i);
#pragma unroll
            for (int q = 0; q < DW; q++) {
                float2 f = uph(w[q]);
                acc[2 * q] = pes * f.x;
                acc[2 * q + 1] = pes * f.y;
            }
        }

        // pass 2: exp + denom + aggregation (8-deep prefetch, pinned)
        for (int cs = beg; cs < end; cs += 64) {
            int cnt = end - cs; if (cnt > 64) cnt = 64;
            float sc = (lane < cnt) ? scores[cs + lane] : -INFINITY;
            int srcl = (lane < cnt) ? csr_src[cs + lane] : 0;
            float pe = __expf(sc - m);
            float zc = pe;
#pragma unroll
            for (int off = 32; off; off >>= 1) zc += __shfl_xor(zc, off, 64);
            z += zc;

            uint32_t A[4][DW], Bv[4][DW];
            auto LD4 = [&](uint32_t (&buf)[4][DW], int t0) {
#pragma unroll
                for (int q = 0; q < 4; q++) {
                    int t = t0 + q;
                    if (t < cnt) {
                        int sx = __builtin_amdgcn_readlane(srcl, t);
                        ldrow(buf[q], sx);
                    }
                }
            };
            auto USE4 = [&](uint32_t (&buf)[4][DW], int t0) {
#pragma unroll
                for (int q = 0; q < 4; q++) {
                    int t = t0 + q;
                    if (t < cnt) {
                        float a = rlanef(pe, t);
#pragma unroll
                        for (int qq = 0; qq < DW; qq++) {
                            float2 f = uph(buf[q][qq]);
                            acc[2 * qq] = fmaf(a, f.x, acc[2 * qq]);
                            acc[2 * qq + 1] = fmaf(a, f.y, acc[2 * qq + 1]);
                        }
                    }
                }
            };
            LD4(A, 0);
            for (int t0 = 0; t0 < cnt; t0 += 8) {
                if (t0 + 4 < cnt) LD4(Bv, t0 + 4);
                __builtin_amdgcn_sched_barrier(0);
                USE4(A, t0);
                if (t0 + 8 < cnt) LD4(A, t0 + 8);
                __builtin_amdgcn_sched_barrier(0);
                USE4(Bv, t0 + 4);
            }
        }

        float rz = 1.0f / z;
        if (act) {
            float o[VEC];
#pragma unroll
            for (int j = 0; j < VEC; j++) {
                o[j] = acc[j] * rz + bv[j];
                if (RELU) o[j] = fmaxf(o[j], 0.0f);
            }
            if constexpr (VEC == 4) {
                *(float4*)(out + (size_t)i * C + lane * 4) = make_float4(o[0], o[1], o[2], o[3]);
            } else {
                *(float2*)(out + (size_t)i * C + lane * 2) = make_float2(o[0], o[1]);
            }
        }
    }
}

// ---------- mean pooling per graph (batch_ids sorted); relu fused; 4-wide MLP ----------
__global__ void k_pool(const float* __restrict__ h, const int* __restrict__ batch,
                       float* __restrict__ pooled) {
    int g = blockIdx.x;
    int lo = 0, hi = NN;
    while (lo < hi) { int mid = (lo + hi) >> 1; if (batch[mid] < g) lo = mid + 1; else hi = mid; }
    int start = lo;
    lo = start; hi = NN;
    while (lo < hi) { int mid = (lo + hi) >> 1; if (batch[mid] < g + 1) lo = mid + 1; else hi = mid; }
    int end = lo;
    float cnt = (float)(end - start);
    int c = threadIdx.x;
    if (c < 200) {
        float a0 = 0.f, a1 = 0.f, a2 = 0.f, a3 = 0.f;
        int i = start;
        for (; i + 4 <= end; i += 4) {
            float v0 = h[(size_t)(i + 0) * 200 + c];
            float v1 = h[(size_t)(i + 1) * 200 + c];
            float v2 = h[(size_t)(i + 2) * 200 + c];
            float v3 = h[(size_t)(i + 3) * 200 + c];
            a0 += fmaxf(v0, 0.0f); a1 += fmaxf(v1, 0.0f);
            a2 += fmaxf(v2, 0.0f); a3 += fmaxf(v3, 0.0f);
        }
        for (; i < end; i++) a0 += fmaxf(h[(size_t)i * 200 + c], 0.0f);
        pooled[g * 200 + c] = ((a0 + a1) + (a2 + a3)) / fmaxf(cnt, 1.0f);
    }
}

// ---------- small dense layers on [G, *] ----------
__global__ void k_mlp(const float* __restrict__ X, const float* __restrict__ W,
                      const float* __restrict__ b, float* __restrict__ Y,
                      int Cin, int Cout, int do_relu) {
    int t = blockIdx.x * blockDim.x + threadIdx.x;
    if (t >= GG * Cout) return;
    int g = t / Cout, j = t - g * Cout;
    const float* xrow = X + (size_t)g * Cin;
    float acc = b[j];
#pragma unroll 4
    for (int k = 0; k < Cin; k++) acc += xrow[k] * W[k * Cout + j];
    if (do_relu) acc = fmaxf(acc, 0.0f);
    Y[t] = acc;
}

extern "C" void kernel_launch(void* const* d_in, const int* in_sizes, int n_in,
                              void* d_out, int out_size, void* d_ws, size_t ws_size,
                              hipStream_t stream) {
    const float* x   = (const float*)d_in[0];
    const int*   ei  = (const int*)d_in[1];
    const float* ea  = (const float*)d_in[2];
    const int*   bat = (const int*)d_in[3];
    const float* W1l = (const float*)d_in[4];  const float* b1l = (const float*)d_in[5];
    const float* W1r = (const float*)d_in[6];  const float* b1r = (const float*)d_in[7];
    const float* W1e = (const float*)d_in[8];
    const float* a1  = (const float*)d_in[9];  const float* c1  = (const float*)d_in[10];
    const float* W2l = (const float*)d_in[11]; const float* b2l = (const float*)d_in[12];
    const float* W2r = (const float*)d_in[13]; const float* b2r = (const float*)d_in[14];
    const float* W2e = (const float*)d_in[15];
    const float* a2  = (const float*)d_in[16]; const float* c2  = (const float*)d_in[17];
    const float* W3  = (const float*)d_in[18]; const float* b3  = (const float*)d_in[19];
    const float* F1  = (const float*)d_in[20]; const float* bf1 = (const float*)d_in[21];
    const float* F2  = (const float*)d_in[22]; const float* bf2 = (const float*)d_in[23];
    const float* F3  = (const float*)d_in[24]; const float* bf3 = (const float*)d_in[25];

    const int* srcv = ei;        // edge_index[0]
    const int* dstv = ei + EE;   // edge_index[1]

    float* W = (float*)d_ws;
    size_t off = 0;
    int*      hist    = (int*)(W + off); off += NN;
    float*    h1      = W + off; off += (size_t)NN * 100;
    float*    h2      = W + off; off += (size_t)NN * 200;
    int*      rowptr  = (int*)(W + off); off += NN + 4;
    int*      cursor  = (int*)(W + off); off += NN;
    int*      bsum    = (int*)(W + off); off += 256;
    float*    scores  = W + off; off += ET;
    int*      csr_src = (int*)(W + off); off += ET;
    int*      csr_dst = (int*)(W + off); off += ET;
    uint32_t* eaa     = (uint32_t*)(W + off); off += (size_t)ET * 12;
    uint32_t* xl16    = (uint32_t*)(W + off); off += (size_t)NN * 100;
    uint32_t* xr16    = (uint32_t*)(W + off); off += (size_t)NN * 100;
    uint32_t* WeT1    = (uint32_t*)(W + off); off += 26 * 40;
    uint32_t* WeT2    = (uint32_t*)(W + off); off += 50 * 40;
    float*    Wc1     = W + off; off += 16 * 256;
    float*    bc1     = W + off; off += 256;
    float*    Wc2     = W + off; off += 100 * 448;
    float*    bc2     = W + off; off += 448;
    float*    pooled  = W + off; off += (size_t)GG * 200;
    float*    p400    = W + off; off += (size_t)GG * 400;
    float*    y1      = W + off; off += (size_t)GG * 200;
    float*    y2      = W + off; off += (size_t)GG * 100;
    (void)ws_size; (void)n_in; (void)in_sizes; (void)out_size;

    const int B = 256;
    const int NODEB = 12500;   // 50000 waves, 1 node each

    // ---- degree histogram + CSR by dst; scatter also packs ea + src/dst ----
    hipMemsetAsync(hist, 0, (size_t)NN * sizeof(int), stream);
    k_hist<<<(EE + B - 1) / B, B, 0, stream>>>(dstv, hist);
    k_scan_a<<<NB, 256, 0, stream>>>(hist, bsum);
    k_scan_b<<<1, 256, 0, stream>>>(bsum, rowptr);
    k_scan_c<<<NB, 256, 0, stream>>>(hist, bsum, rowptr, cursor);
    k_scatter<<<(EE + B - 1) / B, B, 0, stream>>>(srcv, dstv, ea, cursor, csr_src, csr_dst, eaa);
    k_loop2<<<NODEB, B, 0, stream>>>(rowptr, eaa, csr_src, csr_dst);

    // ---- weight prep ----
    k_pack_wet<<<(104 * 10 + B - 1) / B, B, 0, stream>>>(W1e, a1, WeT1, 100, 104);
    k_pack_wet<<<(200 * 10 + B - 1) / B, B, 0, stream>>>(W2e, a2, WeT2, 200, 200);
    k_combine_w<<<(16 * 256 + B - 1) / B, B, 0, stream>>>(W1l, b1l, W1r, b1r, Wc1, bc1, 16, 100, 256);
    k_combine_w<<<(100 * 448 + B - 1) / B, B, 0, stream>>>(W2l, b2l, W2r, b2r, Wc2, bc2, 100, 200, 448);

    // ---- GAT layer 1: 16 -> 100 (RL = 52; pad dwords never read) ----
    {
        dim3 grid((NN + 63) / 64, 256 / 64);
        k_gemm_dual<16, 256, 100, 52><<<grid, 256, 0, stream>>>(x, Wc1, bc1, xl16, xr16);
    }
    k_score_np<100><<<(ET + B - 1) / B, B, 0, stream>>>(csr_src, csr_dst, eaa, WeT1, xl16, xr16, scores);
    k_fin<100, 2, 1><<<NODEB, B, 0, stream>>>(rowptr, csr_src, scores, xl16, c1, h1);

    // ---- GAT layer 2: 100 -> 200 (RL = 100) ----
    {
        dim3 grid((NN + 63) / 64, 448 / 64);
        k_gemm_dual<100, 448, 200, 100><<<grid, 256, 0, stream>>>(h1, Wc2, bc2, xl16, xr16);
    }
    k_score_p<200><<<(ET + B - 1) / B, B, 0, stream>>>(csr_src, csr_dst, eaa, WeT2, xl16, xr16, scores);
    k_fin<200, 4, 0><<<NODEB, B, 0, stream>>>(rowptr, csr_src, scores, xl16, c2, h2);

    // ---- pool (mean over graph, relu fused) then W3 + FFN ----
    k_pool<<<GG, 256, 0, stream>>>(h2, bat, pooled);
    k_mlp<<<(GG * 400 + B - 1) / B, B, 0, stream>>>(pooled, W3, b3, p400, 200, 400, 0);
    k_mlp<<<(GG * 200 + B - 1) / B, B, 0, stream>>>(p400, F1, bf1, y1, 400, 200, 1);
    k_mlp<<<(GG * 100 + B - 1) / B, B, 0, stream>>>(y1, F2, bf2, y2, 200, 100, 1);
    k_mlp<<<(GG * 100 + B - 1) / B, B, 0, stream>>>(y2, F3, bf3, (float*)d_out, 100, 100, 0);
}

// Round 11
// 1153.835 us; speedup vs baseline: 1.4737x; 1.1773x over previous
//
#include <hip/hip_runtime.h>
#include <cstdint>
#include <climits>
#include <math.h>

#define NN 50000
#define EE 1600000
#define ET (EE + NN)   // real edges + one self-loop per node
#define GG 512
#define NEG_SLOPE 0.2f
#define NB 196          // ceil(NN/256) scan blocks

typedef _Float16 half2v __attribute__((ext_vector_type(2)));

__device__ __forceinline__ uint32_t packh2(float a, float b) {
    union { half2v h; uint32_t u; } c;
    c.h = half2v{(_Float16)a, (_Float16)b};
    return c.u;
}
__device__ __forceinline__ float2 uph(uint32_t u) {
    union { uint32_t u; half2v h; } c;
    c.u = u;
    return make_float2((float)c.h.x, (float)c.h.y);
}
__device__ __forceinline__ uint32_t pkadd(uint32_t a, uint32_t b) {
    union { uint32_t u; half2v h; } x, y, z;
    x.u = a; y.u = b;
    z.h = x.h + y.h;    // v_pk_add_f16
    return z.u;
}
__device__ __forceinline__ float fdot2u(uint32_t a, uint32_t b, float c) {
    union { uint32_t u; half2v h; } ua, ub;
    ua.u = a; ub.u = b;
    return __builtin_amdgcn_fdot2(ua.h, ub.h, c, false);
}
__device__ __forceinline__ float rlanef(float v, int l) {
    return __int_as_float(__builtin_amdgcn_readlane(__float_as_int(v), l));
}

// ---------- degree histogram ----------
__global__ void k_hist(const int* __restrict__ dst, int* __restrict__ hist) {
    int e = blockIdx.x * blockDim.x + threadIdx.x;
    if (e < EE) atomicAdd(&hist[dst[e]], 1);
}

// ---------- CSR build ----------
__global__ void k_scan_a(const int* __restrict__ hist, int* __restrict__ bsum) {
    __shared__ int tmp[256];
    int i = blockIdx.x * 256 + threadIdx.x;
    tmp[threadIdx.x] = (i < NN) ? hist[i] : 0;
    __syncthreads();
    for (int d = 128; d; d >>= 1) {
        if (threadIdx.x < d) tmp[threadIdx.x] += tmp[threadIdx.x + d];
        __syncthreads();
    }
    if (threadIdx.x == 0) bsum[blockIdx.x] = tmp[0];
}

__global__ void k_scan_b(int* __restrict__ bsum, int* __restrict__ rowptr) {
    __shared__ int tmp[256];
    int t = threadIdx.x;
    int v = (t < NB) ? bsum[t] : 0;
    tmp[t] = v;
    __syncthreads();
    for (int d = 1; d < 256; d <<= 1) {
        int u = (t >= d) ? tmp[t - d] : 0;
        __syncthreads();
        tmp[t] += u;
        __syncthreads();
    }
    if (t < NB) bsum[t] = tmp[t] - v;        // exclusive
    if (t == 255) rowptr[NN] = tmp[255];     // total == EE
}

// rowptr + cursor init fused
__global__ void k_scan_c(const int* __restrict__ hist, const int* __restrict__ bsum,
                         int* __restrict__ rowptr, int* __restrict__ cursor) {
    __shared__ int tmp[256];
    int i = blockIdx.x * 256 + threadIdx.x;
    int v = (i < NN) ? hist[i] : 0;
    tmp[threadIdx.x] = v;
    __syncthreads();
    for (int d = 1; d < 256; d <<= 1) {
        int t = (threadIdx.x >= d) ? tmp[threadIdx.x - d] : 0;
        __syncthreads();
        tmp[threadIdx.x] += t;
        __syncthreads();
    }
    if (i < NN) {
        int rp = tmp[threadIdx.x] - v + bsum[blockIdx.x];
        rowptr[i] = rp;
        cursor[i] = rp;
    }
}

// ---------- scatter + csr_src/csr_dst + fp16 AoS ea pack, one pass ----------
__global__ void k_scatter(const int* __restrict__ srcv, const int* __restrict__ dstv,
                          const float* __restrict__ ea, int* __restrict__ cursor,
                          int* __restrict__ csr_src, int* __restrict__ csr_dst,
                          uint32_t* __restrict__ eaa) {
    int e = blockIdx.x * blockDim.x + threadIdx.x;
    if (e >= EE) return;
    int d = dstv[e];
    int p = atomicAdd(&cursor[d], 1);
    csr_src[p] = srcv[e];
    csr_dst[p] = d;
    const float* r = ea + (size_t)e * 18;
    uint32_t o[12];
#pragma unroll
    for (int kk = 0; kk < 9; kk++) {
        float2 q = *(const float2*)(r + 2 * kk);
        o[kk] = packh2(q.x, q.y);
    }
    o[9] = o[10] = o[11] = 0;
    uint4* dst = (uint4*)(eaa + (size_t)p * 12);
    dst[0] = *(uint4*)&o[0];
    dst[1] = *(uint4*)&o[4];
    dst[2] = *(uint4*)&o[8];
}

// ---------- self-loop edge attr = mean of incoming ea; append virtual edges ----------
__global__ void __launch_bounds__(256)
k_loop2(const int* __restrict__ rowptr, uint32_t* __restrict__ eaa,
        int* __restrict__ csr_src, int* __restrict__ csr_dst) {
    const int lane = threadIdx.x & 63;
    int wid = blockIdx.x * (blockDim.x >> 6) + (threadIdx.x >> 6);
    int nw = gridDim.x * (blockDim.x >> 6);

    for (int i = wid; i < NN; i += nw) {
        int beg = __builtin_amdgcn_readfirstlane(rowptr[i]);
        int end = __builtin_amdgcn_readfirstlane(rowptr[i + 1]);
        float s[18];
#pragma unroll
        for (int j = 0; j < 18; j++) s[j] = 0.f;
        for (int cs = beg; cs < end; cs += 64) {
            int cnt = end - cs; if (cnt > 64) cnt = 64;
            if (lane < cnt) {
                const uint32_t* pe = eaa + (size_t)(cs + lane) * 12;
                uint4 a = *(const uint4*)pe;
                uint4 b = *(const uint4*)(pe + 4);
                uint32_t c = pe[8];
                uint32_t w[9] = {a.x, a.y, a.z, a.w, b.x, b.y, b.z, b.w, c};
#pragma unroll
                for (int kk = 0; kk < 9; kk++) {
                    float2 q = uph(w[kk]);
                    s[2 * kk] += q.x; s[2 * kk + 1] += q.y;
                }
            }
        }
#pragma unroll
        for (int j = 0; j < 18; j++) {
#pragma unroll
            for (int off = 32; off; off >>= 1) s[j] += __shfl_xor(s[j], off, 64);
        }
        if (lane == 0) {
            int deg = end - beg;
            float rd = (deg > 0) ? 1.0f / (float)deg : 0.0f;
            uint32_t o[12];
#pragma unroll
            for (int kk = 0; kk < 9; kk++) o[kk] = packh2(s[2 * kk] * rd, s[2 * kk + 1] * rd);
            o[9] = o[10] = o[11] = 0;
            uint4* dst = (uint4*)(eaa + (size_t)(EE + i) * 12);
            dst[0] = *(uint4*)&o[0];
            dst[1] = *(uint4*)&o[4];
            dst[2] = *(uint4*)&o[8];
            csr_src[EE + i] = i; csr_dst[EE + i] = i;
        }
    }
}

// ---------- pack WeT (zero-padded to CP cols): per col: 9 fp16-pair dwords + att ----------
__global__ void k_pack_wet(const float* __restrict__ We, const float* __restrict__ att,
                           uint32_t* __restrict__ WeT, int C, int CP) {
    int t = blockIdx.x * blockDim.x + threadIdx.x;
    if (t >= CP * 10) return;
    int c = t / 10, kk = t - c * 10;
    int g = c >> 2, j = c & 3;
    uint32_t v = 0;
    if (c < C) {
        if (kk < 9) v = packh2(We[(2 * kk) * C + c], We[(2 * kk + 1) * C + c]);
        else v = __float_as_uint(att[c]);
    }
    WeT[g * 40 + j * 10 + kk] = v;
}

// ---------- combine Wl|Wr into padded Wc [K x NP], biases into bc [NP] ----------
__global__ void k_combine_w(const float* __restrict__ Wl, const float* __restrict__ bl,
                            const float* __restrict__ Wr, const float* __restrict__ br,
                            float* __restrict__ Wc, float* __restrict__ bc,
                            int K, int C, int NP) {
    int t = blockIdx.x * blockDim.x + threadIdx.x;
    if (t < K * NP) {
        int k = t / NP, n = t - k * NP;
        float v = 0.0f;
        if (n < C) v = Wl[k * C + n];
        else if (n < 2 * C) v = Wr[k * C + n - C];
        Wc[t] = v;
    }
    if (t < NP) {
        float v = 0.0f;
        if (t < C) v = bl[t];
        else if (t < 2 * C) v = br[t - C];
        bc[t] = v;
    }
}

// ---------- tiled dual GEMM -> xl16/xr16 (packed fp16, padded pitch RL) ----------
template <int KK, int NP, int C, int RL>
__global__ void __launch_bounds__(256)
k_gemm_dual(const float* __restrict__ A, const float* __restrict__ Wc,
            const float* __restrict__ bc,
            uint32_t* __restrict__ xl16, uint32_t* __restrict__ xr16) {
    constexpr int BM = 64, BN = 64, BK = 16;
    __shared__ float As[BK][BM];
    __shared__ float Ws[BK][BN];
    const int tidx = threadIdx.x;
    const int tx = tidx & 15;
    const int ty = tidx >> 4;
    const int m0 = blockIdx.x * BM;
    const int n0 = blockIdx.y * BN;

    float acc[4][4];
#pragma unroll
    for (int i2 = 0; i2 < 4; i2++)
#pragma unroll
        for (int j2 = 0; j2 < 4; j2++) acc[i2][j2] = 0.0f;

    for (int k0 = 0; k0 < KK; k0 += BK) {
        {
            int m = tidx >> 2;
            int kq = (tidx & 3) * 4;
            float4 v = make_float4(0.f, 0.f, 0.f, 0.f);
            if (m0 + m < NN && k0 + kq < KK)
                v = *(const float4*)(A + (size_t)(m0 + m) * KK + k0 + kq);
            As[kq + 0][m] = v.x; As[kq + 1][m] = v.y;
            As[kq + 2][m] = v.z; As[kq + 3][m] = v.w;
        }
        {
            int k = tidx >> 4;
            int nq = (tidx & 15) * 4;
            float4 v = make_float4(0.f, 0.f, 0.f, 0.f);
            if (k0 + k < KK)
                v = *(const float4*)(Wc + (size_t)(k0 + k) * NP + n0 + nq);
            *(float4*)&Ws[k][nq] = v;
        }
        __syncthreads();
#pragma unroll
        for (int k = 0; k < BK; k++) {
            float a[4], b[4];
            *(float4*)a = *(const float4*)&As[k][ty * 4];
            *(float4*)b = *(const float4*)&Ws[k][tx * 4];
#pragma unroll
            for (int i2 = 0; i2 < 4; i2++)
#pragma unroll
                for (int j2 = 0; j2 < 4; j2++) acc[i2][j2] += a[i2] * b[j2];
        }
        __syncthreads();
    }

    const int n = n0 + tx * 4;
    float4 bcv = *(const float4*)(bc + n);
#pragma unroll
    for (int i2 = 0; i2 < 4; i2++) {
        int m = m0 + ty * 4 + i2;
        if (m >= NN) continue;
        float4 o = make_float4(acc[i2][0] + bcv.x, acc[i2][1] + bcv.y,
                               acc[i2][2] + bcv.z, acc[i2][3] + bcv.w);
        uint2 p;
        p.x = packh2(o.x, o.y);
        p.y = packh2(o.z, o.w);
        if (n < C)          *(uint2*)(xl16 + (size_t)m * RL + n / 2) = p;
        else if (n < 2 * C) *(uint2*)(xr16 + (size_t)m * RL + (n - C) / 2) = p;
    }
}

// ---------- edge-parallel scores, UNPINNED (R2 structure, FULL unroll) ----------
// Full unroll => compile-time register indices (no scratch), compiler JIT-pipelines
// loads into the compute stream; ~6 waves/SIMD provide MLP via occupancy.
template <int C>
__global__ void __launch_bounds__(256)
k_score_np(const int* __restrict__ csr_src, const int* __restrict__ csr_dst,
           const uint32_t* __restrict__ eaa, const uint32_t* __restrict__ WeT,
           const uint32_t* __restrict__ xl16, const uint32_t* __restrict__ xr16,
           float* __restrict__ scores) {
    constexpr int RL = ((C / 2) + 3) & ~3;   // padded dwords per row
    int pos = blockIdx.x * blockDim.x + threadIdx.x;
    if (pos >= ET) return;
    int s = csr_src[pos];
    int d = csr_dst[pos];

    uint32_t lw[RL], rw[RL];
    const uint4* pl = (const uint4*)(xl16 + (size_t)s * RL);
    const uint4* pr = (const uint4*)(xr16 + (size_t)d * RL);
#pragma unroll
    for (int i = 0; i < RL / 4; i++) *(uint4*)&lw[4 * i] = pl[i];
#pragma unroll
    for (int i = 0; i < RL / 4; i++) *(uint4*)&rw[4 * i] = pr[i];
    const uint32_t* pe = eaa + (size_t)pos * 12;
    uint4 e0 = *(const uint4*)pe;
    uint4 e1 = *(const uint4*)(pe + 4);
    uint32_t e8 = pe[8];
    uint32_t ean[9] = {e0.x, e0.y, e0.z, e0.w, e1.x, e1.y, e1.z, e1.w, e8};

    float score = 0.0f;
#pragma unroll
    for (int g = 0; g < C / 4; g++) {        // FULL unroll: static reg indices
        const uint32_t* wg = WeT + g * 40;   // wave-uniform -> scalar loads
        uint32_t u0 = pkadd(lw[2 * g], rw[2 * g]);
        uint32_t u1 = pkadd(lw[2 * g + 1], rw[2 * g + 1]);
        float2 f0 = uph(u0), f1 = uph(u1);
        float lv[4] = {f0.x, f0.y, f1.x, f1.y};
#pragma unroll
        for (int j = 0; j < 4; j++) {
            float w = 0.0f;
#pragma unroll
            for (int kk = 0; kk < 9; kk++) w = fdot2u(ean[kk], wg[j * 10 + kk], w);
            float u = lv[j] + w;
            float h = fmaxf(u, NEG_SLOPE * u);
            score = fmaf(__uint_as_float(wg[j * 10 + 9]), h, score);
        }
    }
    scores[pos] = score;
}

// ---------- edge-parallel scores, PINNED preload (kept for C=200) ----------
template <int C>
__global__ void __launch_bounds__(256, 2)
k_score_p(const int* __restrict__ csr_src, const int* __restrict__ csr_dst,
          const uint32_t* __restrict__ eaa, const uint32_t* __restrict__ WeT,
          const uint32_t* __restrict__ xl16, const uint32_t* __restrict__ xr16,
          float* __restrict__ scores) {
    constexpr int RL = ((C / 2) + 3) & ~3;
    int pos = blockIdx.x * blockDim.x + threadIdx.x;
    if (pos >= ET) return;
    int s = csr_src[pos];
    int d = csr_dst[pos];

    uint32_t lw[RL], rw[RL];
    const uint4* pl = (const uint4*)(xl16 + (size_t)s * RL);
    const uint4* pr = (const uint4*)(xr16 + (size_t)d * RL);
#pragma unroll
    for (int i = 0; i < RL / 4; i++) *(uint4*)&lw[4 * i] = pl[i];
#pragma unroll
    for (int i = 0; i < RL / 4; i++) *(uint4*)&rw[4 * i] = pr[i];
    const uint32_t* pe = eaa + (size_t)pos * 12;
    uint4 e0 = *(const uint4*)pe;
    uint4 e1 = *(const uint4*)(pe + 4);
    uint32_t e8 = pe[8];
    __builtin_amdgcn_sched_barrier(0);   // pin: loads issued before compute

    uint32_t ean[9] = {e0.x, e0.y, e0.z, e0.w, e1.x, e1.y, e1.z, e1.w, e8};

    float score = 0.0f;
#pragma unroll
    for (int g = 0; g < C / 4; g++) {
        const uint32_t* wg = WeT + g * 40;
        uint32_t u0 = pkadd(lw[2 * g], rw[2 * g]);
        uint32_t u1 = pkadd(lw[2 * g + 1], rw[2 * g + 1]);
        float2 f0 = uph(u0), f1 = uph(u1);
        float lv[4] = {f0.x, f0.y, f1.x, f1.y};
#pragma unroll
        for (int j = 0; j < 4; j++) {
            float w = 0.0f;
#pragma unroll
            for (int kk = 0; kk < 9; kk++) w = fdot2u(ean[kk], wg[j * 10 + kk], w);
            float u = lv[j] + w;
            float h = fmaxf(u, NEG_SLOPE * u);
            score = fmaf(__uint_as_float(wg[j * 10 + 9]), h, score);
        }
    }
    scores[pos] = score;
}

// ---------- per-node exact softmax + aggregation from fp16 rows (R3 structure) ------
template <int C, int VEC, int RELU>
__global__ void __launch_bounds__(256)
k_fin(const int* __restrict__ rowptr, const int* __restrict__ csr_src,
      const float* __restrict__ scores, const uint32_t* __restrict__ xl16,
      const float* __restrict__ bias, float* __restrict__ out) {
    constexpr int DW = VEC / 2;              // dwords per lane per row
    constexpr int RL = ((C / 2) + 3) & ~3;   // row pitch in dwords
    constexpr int NL = C / VEC;
    const int lane = threadIdx.x & 63;
    int wid = blockIdx.x * (blockDim.x >> 6) + (threadIdx.x >> 6);
    int nw = gridDim.x * (blockDim.x >> 6);
    const bool act = lane < NL;

    float bv[VEC];
    if (act) {
#pragma unroll
        for (int j = 0; j < VEC; j++) bv[j] = bias[lane * VEC + j];
    } else {
#pragma unroll
        for (int j = 0; j < VEC; j++) bv[j] = 0.f;
    }

    auto ldrow = [&](uint32_t (&buf)[DW], int node) {
        if (act) {
            if constexpr (DW == 2) {
                uint2 v = *(const uint2*)(xl16 + (size_t)node * RL + lane * 2);
                buf[0] = v.x; buf[1] = v.y;
            } else {
                buf[0] = xl16[(size_t)node * RL + lane];
            }
        } else {
#pragma unroll
            for (int q = 0; q < DW; q++) buf[q] = 0;
        }
    };

    for (int i = wid; i < NN; i += nw) {
        int beg = __builtin_amdgcn_readfirstlane(rowptr[i]);
        int end = __builtin_amdgcn_readfirstlane(rowptr[i + 1]);
        float s_self = scores[EE + i];

        // pass 1: exact max
        float m = s_self;
        for (int cs = beg; cs < end; cs += 64) {
            int cnt = end - cs; if (cnt > 64) cnt = 64;
            float sc = (lane < cnt) ? scores[cs + lane] : -INFINITY;
#pragma unroll
            for (int off = 32; off; off >>= 1) sc = fmaxf(sc, __shfl_xor(sc, off, 64));
            m = fmaxf(m, sc);
        }

        // self-loop contribution
        float acc[VEC];
        float pes = __expf(s_self - m);
        float z = pes;
        {
            uint32_t w[DW];
            ldrow(w, i);
#pragma unroll
            for (int q = 0; q < DW; q++) {
                float2 f = uph(w[q]);
                acc[2 * q] = pes * f.x;
                acc[2 * q + 1] = pes * f.y;
            }
        }

        // pass 2: exp + denom + aggregation (8-deep prefetch, pinned)
        for (int cs = beg; cs < end; cs += 64) {
            int cnt = end - cs; if (cnt > 64) cnt = 64;
            float sc = (lane < cnt) ? scores[cs + lane] : -INFINITY;
            int srcl = (lane < cnt) ? csr_src[cs + lane] : 0;
            float pe = __expf(sc - m);
            float zc = pe;
#pragma unroll
            for (int off = 32; off; off >>= 1) zc += __shfl_xor(zc, off, 64);
            z += zc;

            uint32_t A[4][DW], Bv[4][DW];
            auto LD4 = [&](uint32_t (&buf)[4][DW], int t0) {
#pragma unroll
                for (int q = 0; q < 4; q++) {
                    int t = t0 + q;
                    if (t < cnt) {
                        int sx = __builtin_amdgcn_readlane(srcl, t);
                        ldrow(buf[q], sx);
                    }
                }
            };
            auto USE4 = [&](uint32_t (&buf)[4][DW], int t0) {
#pragma unroll
                for (int q = 0; q < 4; q++) {
                    int t = t0 + q;
                    if (t < cnt) {
                        float a = rlanef(pe, t);
#pragma unroll
                        for (int qq = 0; qq < DW; qq++) {
                            float2 f = uph(buf[q][qq]);
                            acc[2 * qq] = fmaf(a, f.x, acc[2 * qq]);
                            acc[2 * qq + 1] = fmaf(a, f.y, acc[2 * qq + 1]);
                        }
                    }
                }
            };
            LD4(A, 0);
            for (int t0 = 0; t0 < cnt; t0 += 8) {
                if (t0 + 4 < cnt) LD4(Bv, t0 + 4);
                __builtin_amdgcn_sched_barrier(0);
                USE4(A, t0);
                if (t0 + 8 < cnt) LD4(A, t0 + 8);
                __builtin_amdgcn_sched_barrier(0);
                USE4(Bv, t0 + 4);
            }
        }

        float rz = 1.0f / z;
        if (act) {
            float o[VEC];
#pragma unroll
            for (int j = 0; j < VEC; j++) {
                o[j] = acc[j] * rz + bv[j];
                if (RELU) o[j] = fmaxf(o[j], 0.0f);
            }
            if constexpr (VEC == 4) {
                *(float4*)(out + (size_t)i * C + lane * 4) = make_float4(o[0], o[1], o[2], o[3]);
            } else {
                *(float2*)(out + (size_t)i * C + lane * 2) = make_float2(o[0], o[1]);
            }
        }
    }
}

// ---------- mean pooling per graph (batch_ids sorted); relu fused; 4-wide MLP ----------
__global__ void k_pool(const float* __restrict__ h, const int* __restrict__ batch,
                       float* __restrict__ pooled) {
    int g = blockIdx.x;
    int lo = 0, hi = NN;
    while (lo < hi) { int mid = (lo + hi) >> 1; if (batch[mid] < g) lo = mid + 1; else hi = mid; }
    int start = lo;
    lo = start; hi = NN;
    while (lo < hi) { int mid = (lo + hi) >> 1; if (batch[mid] < g + 1) lo = mid + 1; else hi = mid; }
    int end = lo;
    float cnt = (float)(end - start);
    int c = threadIdx.x;
    if (c < 200) {
        float a0 = 0.f, a1 = 0.f, a2 = 0.f, a3 = 0.f;
        int i = start;
        for (; i + 4 <= end; i += 4) {
            float v0 = h[(size_t)(i + 0) * 200 + c];
            float v1 = h[(size_t)(i + 1) * 200 + c];
            float v2 = h[(size_t)(i + 2) * 200 + c];
            float v3 = h[(size_t)(i + 3) * 200 + c];
            a0 += fmaxf(v0, 0.0f); a1 += fmaxf(v1, 0.0f);
            a2 += fmaxf(v2, 0.0f); a3 += fmaxf(v3, 0.0f);
        }
        for (; i < end; i++) a0 += fmaxf(h[(size_t)i * 200 + c], 0.0f);
        pooled[g * 200 + c] = ((a0 + a1) + (a2 + a3)) / fmaxf(cnt, 1.0f);
    }
}

// ---------- small dense layers on [G, *] ----------
__global__ void k_mlp(const float* __restrict__ X, const float* __restrict__ W,
                      const float* __restrict__ b, float* __restrict__ Y,
                      int Cin, int Cout, int do_relu) {
    int t = blockIdx.x * blockDim.x + threadIdx.x;
    if (t >= GG * Cout) return;
    int g = t / Cout, j = t - g * Cout;
    const float* xrow = X + (size_t)g * Cin;
    float acc = b[j];
#pragma unroll 4
    for (int k = 0; k < Cin; k++) acc += xrow[k] * W[k * Cout + j];
    if (do_relu) acc = fmaxf(acc, 0.0f);
    Y[t] = acc;
}

extern "C" void kernel_launch(void* const* d_in, const int* in_sizes, int n_in,
                              void* d_out, int out_size, void* d_ws, size_t ws_size,
                              hipStream_t stream) {
    const float* x   = (const float*)d_in[0];
    const int*   ei  = (const int*)d_in[1];
    const float* ea  = (const float*)d_in[2];
    const int*   bat = (const int*)d_in[3];
    const float* W1l = (const float*)d_in[4];  const float* b1l = (const float*)d_in[5];
    const float* W1r = (const float*)d_in[6];  const float* b1r = (const float*)d_in[7];
    const float* W1e = (const float*)d_in[8];
    const float* a1  = (const float*)d_in[9];  const float* c1  = (const float*)d_in[10];
    const float* W2l = (const float*)d_in[11]; const float* b2l = (const float*)d_in[12];
    const float* W2r = (const float*)d_in[13]; const float* b2r = (const float*)d_in[14];
    const float* W2e = (const float*)d_in[15];
    const float* a2  = (const float*)d_in[16]; const float* c2  = (const float*)d_in[17];
    const float* W3  = (const float*)d_in[18]; const float* b3  = (const float*)d_in[19];
    const float* F1  = (const float*)d_in[20]; const float* bf1 = (const float*)d_in[21];
    const float* F2  = (const float*)d_in[22]; const float* bf2 = (const float*)d_in[23];
    const float* F3  = (const float*)d_in[24]; const float* bf3 = (const float*)d_in[25];

    const int* srcv = ei;        // edge_index[0]
    const int* dstv = ei + EE;   // edge_index[1]

    float* W = (float*)d_ws;
    size_t off = 0;
    int*      hist    = (int*)(W + off); off += NN;
    float*    h1      = W + off; off += (size_t)NN * 100;
    float*    h2      = W + off; off += (size_t)NN * 200;
    int*      rowptr  = (int*)(W + off); off += NN + 4;
    int*      cursor  = (int*)(W + off); off += NN;
    int*      bsum    = (int*)(W + off); off += 256;
    float*    scores  = W + off; off += ET;
    int*      csr_src = (int*)(W + off); off += ET;
    int*      csr_dst = (int*)(W + off); off += ET;
    uint32_t* eaa     = (uint32_t*)(W + off); off += (size_t)ET * 12;
    uint32_t* xl16    = (uint32_t*)(W + off); off += (size_t)NN * 100;
    uint32_t* xr16    = (uint32_t*)(W + off); off += (size_t)NN * 100;
    uint32_t* WeT1    = (uint32_t*)(W + off); off += 26 * 40;
    uint32_t* WeT2    = (uint32_t*)(W + off); off += 50 * 40;
    float*    Wc1     = W + off; off += 16 * 256;
    float*    bc1     = W + off; off += 256;
    float*    Wc2     = W + off; off += 100 * 448;
    float*    bc2     = W + off; off += 448;
    float*    pooled  = W + off; off += (size_t)GG * 200;
    float*    p400    = W + off; off += (size_t)GG * 400;
    float*    y1      = W + off; off += (size_t)GG * 200;
    float*    y2      = W + off; off += (size_t)GG * 100;
    (void)ws_size; (void)n_in; (void)in_sizes; (void)out_size;

    const int B = 256;
    const int NODEB = 12500;   // 50000 waves, 1 node each

    // ---- degree histogram + CSR by dst; scatter also packs ea + src/dst ----
    hipMemsetAsync(hist, 0, (size_t)NN * sizeof(int), stream);
    k_hist<<<(EE + B - 1) / B, B, 0, stream>>>(dstv, hist);
    k_scan_a<<<NB, 256, 0, stream>>>(hist, bsum);
    k_scan_b<<<1, 256, 0, stream>>>(bsum, rowptr);
    k_scan_c<<<NB, 256, 0, stream>>>(hist, bsum, rowptr, cursor);
    k_scatter<<<(EE + B - 1) / B, B, 0, stream>>>(srcv, dstv, ea, cursor, csr_src, csr_dst, eaa);
    k_loop2<<<NODEB, B, 0, stream>>>(rowptr, eaa, csr_src, csr_dst);

    // ---- weight prep ----
    k_pack_wet<<<(104 * 10 + B - 1) / B, B, 0, stream>>>(W1e, a1, WeT1, 100, 104);
    k_pack_wet<<<(200 * 10 + B - 1) / B, B, 0, stream>>>(W2e, a2, WeT2, 200, 200);
    k_combine_w<<<(16 * 256 + B - 1) / B, B, 0, stream>>>(W1l, b1l, W1r, b1r, Wc1, bc1, 16, 100, 256);
    k_combine_w<<<(100 * 448 + B - 1) / B, B, 0, stream>>>(W2l, b2l, W2r, b2r, Wc2, bc2, 100, 200, 448);

    // ---- GAT layer 1: 16 -> 100 (RL = 52; pad dwords never read) ----
    {
        dim3 grid((NN + 63) / 64, 256 / 64);
        k_gemm_dual<16, 256, 100, 52><<<grid, 256, 0, stream>>>(x, Wc1, bc1, xl16, xr16);
    }
    k_score_np<100><<<(ET + B - 1) / B, B, 0, stream>>>(csr_src, csr_dst, eaa, WeT1, xl16, xr16, scores);
    k_fin<100, 2, 1><<<NODEB, B, 0, stream>>>(rowptr, csr_src, scores, xl16, c1, h1);

    // ---- GAT layer 2: 100 -> 200 (RL = 100) ----
    {
        dim3 grid((NN + 63) / 64, 448 / 64);
        k_gemm_dual<100, 448, 200, 100><<<grid, 256, 0, stream>>>(h1, Wc2, bc2, xl16, xr16);
    }
    k_score_p<200><<<(ET + B - 1) / B, B, 0, stream>>>(csr_src, csr_dst, eaa, WeT2, xl16, xr16, scores);
    k_fin<200, 4, 0><<<NODEB, B, 0, stream>>>(rowptr, csr_src, scores, xl16, c2, h2);

    // ---- pool (mean over graph, relu fused) then W3 + FFN ----
    k_pool<<<GG, 256, 0, stream>>>(h2, bat, pooled);
    k_mlp<<<(GG * 400 + B - 1) / B, B, 0, stream>>>(pooled, W3, b3, p400, 200, 400, 0);
    k_mlp<<<(GG * 200 + B - 1) / B, B, 0, stream>>>(p400, F1, bf1, y1, 400, 200, 1);
    k_mlp<<<(GG * 100 + B - 1) / B, B, 0, stream>>>(y1, F2, bf2, y2, 200, 100, 1);
    k_mlp<<<(GG * 100 + B - 1) / B, B, 0, stream>>>(y2, F3, bf3, (float*)d_out, 100, 100, 0);
}

// Round 12
// 1148.128 us; speedup vs baseline: 1.4810x; 1.0050x over previous
//
#include <hip/hip_runtime.h>
#include <cstdint>
#include <climits>
#include <math.h>

#define NN 50000
#define EE 1600000
#define ET (EE + NN)   // real edges + one self-loop per node
#define GG 512
#define NEG_SLOPE 0.2f
#define NB 196          // ceil(NN/256) scan blocks

typedef _Float16 half2v __attribute__((ext_vector_type(2)));

__device__ __forceinline__ uint32_t packh2(float a, float b) {
    union { half2v h; uint32_t u; } c;
    c.h = half2v{(_Float16)a, (_Float16)b};
    return c.u;
}
__device__ __forceinline__ float2 uph(uint32_t u) {
    union { uint32_t u; half2v h; } c;
    c.u = u;
    return make_float2((float)c.h.x, (float)c.h.y);
}
__device__ __forceinline__ uint32_t pkadd(uint32_t a, uint32_t b) {
    union { uint32_t u; half2v h; } x, y, z;
    x.u = a; y.u = b;
    z.h = x.h + y.h;    // v_pk_add_f16
    return z.u;
}
__device__ __forceinline__ float fdot2u(uint32_t a, uint32_t b, float c) {
    union { uint32_t u; half2v h; } ua, ub;
    ua.u = a; ub.u = b;
    return __builtin_amdgcn_fdot2(ua.h, ub.h, c, false);
}
__device__ __forceinline__ float rlanef(float v, int l) {
    return __int_as_float(__builtin_amdgcn_readlane(__float_as_int(v), l));
}

// ---------- degree histogram ----------
__global__ void k_hist(const int* __restrict__ dst, int* __restrict__ hist) {
    int e = blockIdx.x * blockDim.x + threadIdx.x;
    if (e < EE) atomicAdd(&hist[dst[e]], 1);
}

// ---------- CSR build ----------
__global__ void k_scan_a(const int* __restrict__ hist, int* __restrict__ bsum) {
    __shared__ int tmp[256];
    int i = blockIdx.x * 256 + threadIdx.x;
    tmp[threadIdx.x] = (i < NN) ? hist[i] : 0;
    __syncthreads();
    for (int d = 128; d; d >>= 1) {
        if (threadIdx.x < d) tmp[threadIdx.x] += tmp[threadIdx.x + d];
        __syncthreads();
    }
    if (threadIdx.x == 0) bsum[blockIdx.x] = tmp[0];
}

__global__ void k_scan_b(int* __restrict__ bsum, int* __restrict__ rowptr) {
    __shared__ int tmp[256];
    int t = threadIdx.x;
    int v = (t < NB) ? bsum[t] : 0;
    tmp[t] = v;
    __syncthreads();
    for (int d = 1; d < 256; d <<= 1) {
        int u = (t >= d) ? tmp[t - d] : 0;
        __syncthreads();
        tmp[t] += u;
        __syncthreads();
    }
    if (t < NB) bsum[t] = tmp[t] - v;        // exclusive
    if (t == 255) rowptr[NN] = tmp[255];     // total == EE
}

// rowptr + cursor init fused
__global__ void k_scan_c(const int* __restrict__ hist, const int* __restrict__ bsum,
                         int* __restrict__ rowptr, int* __restrict__ cursor) {
    __shared__ int tmp[256];
    int i = blockIdx.x * 256 + threadIdx.x;
    int v = (i < NN) ? hist[i] : 0;
    tmp[threadIdx.x] = v;
    __syncthreads();
    for (int d = 1; d < 256; d <<= 1) {
        int t = (threadIdx.x >= d) ? tmp[threadIdx.x - d] : 0;
        __syncthreads();
        tmp[threadIdx.x] += t;
        __syncthreads();
    }
    if (i < NN) {
        int rp = tmp[threadIdx.x] - v + bsum[blockIdx.x];
        rowptr[i] = rp;
        cursor[i] = rp;
    }
}

// ---------- scatter + csr_src/csr_dst + fp16 AoS ea pack, one pass ----------
__global__ void k_scatter(const int* __restrict__ srcv, const int* __restrict__ dstv,
                          const float* __restrict__ ea, int* __restrict__ cursor,
                          int* __restrict__ csr_src, int* __restrict__ csr_dst,
                          uint32_t* __restrict__ eaa) {
    int e = blockIdx.x * blockDim.x + threadIdx.x;
    if (e >= EE) return;
    int d = dstv[e];
    int p = atomicAdd(&cursor[d], 1);
    csr_src[p] = srcv[e];
    csr_dst[p] = d;
    const float* r = ea + (size_t)e * 18;
    uint32_t o[12];
#pragma unroll
    for (int kk = 0; kk < 9; kk++) {
        float2 q = *(const float2*)(r + 2 * kk);
        o[kk] = packh2(q.x, q.y);
    }
    o[9] = o[10] = o[11] = 0;
    uint4* dst = (uint4*)(eaa + (size_t)p * 12);
    dst[0] = *(uint4*)&o[0];
    dst[1] = *(uint4*)&o[4];
    dst[2] = *(uint4*)&o[8];
}

// ---------- self-loop edge attr = mean of incoming ea; append virtual edges ----------
__global__ void __launch_bounds__(256)
k_loop2(const int* __restrict__ rowptr, uint32_t* __restrict__ eaa,
        int* __restrict__ csr_src, int* __restrict__ csr_dst) {
    const int lane = threadIdx.x & 63;
    int wid = blockIdx.x * (blockDim.x >> 6) + (threadIdx.x >> 6);
    int nw = gridDim.x * (blockDim.x >> 6);

    for (int i = wid; i < NN; i += nw) {
        int beg = __builtin_amdgcn_readfirstlane(rowptr[i]);
        int end = __builtin_amdgcn_readfirstlane(rowptr[i + 1]);
        float s[18];
#pragma unroll
        for (int j = 0; j < 18; j++) s[j] = 0.f;
        for (int cs = beg; cs < end; cs += 64) {
            int cnt = end - cs; if (cnt > 64) cnt = 64;
            if (lane < cnt) {
                const uint32_t* pe = eaa + (size_t)(cs + lane) * 12;
                uint4 a = *(const uint4*)pe;
                uint4 b = *(const uint4*)(pe + 4);
                uint32_t c = pe[8];
                uint32_t w[9] = {a.x, a.y, a.z, a.w, b.x, b.y, b.z, b.w, c};
#pragma unroll
                for (int kk = 0; kk < 9; kk++) {
                    float2 q = uph(w[kk]);
                    s[2 * kk] += q.x; s[2 * kk + 1] += q.y;
                }
            }
        }
#pragma unroll
        for (int j = 0; j < 18; j++) {
#pragma unroll
            for (int off = 32; off; off >>= 1) s[j] += __shfl_xor(s[j], off, 64);
        }
        if (lane == 0) {
            int deg = end - beg;
            float rd = (deg > 0) ? 1.0f / (float)deg : 0.0f;
            uint32_t o[12];
#pragma unroll
            for (int kk = 0; kk < 9; kk++) o[kk] = packh2(s[2 * kk] * rd, s[2 * kk + 1] * rd);
            o[9] = o[10] = o[11] = 0;
            uint4* dst = (uint4*)(eaa + (size_t)(EE + i) * 12);
            dst[0] = *(uint4*)&o[0];
            dst[1] = *(uint4*)&o[4];
            dst[2] = *(uint4*)&o[8];
            csr_src[EE + i] = i; csr_dst[EE + i] = i;
        }
    }
}

// ---------- pack WeT (zero-padded to CP cols): per col: 9 fp16-pair dwords + att ----------
__global__ void k_pack_wet(const float* __restrict__ We, const float* __restrict__ att,
                           uint32_t* __restrict__ WeT, int C, int CP) {
    int t = blockIdx.x * blockDim.x + threadIdx.x;
    if (t >= CP * 10) return;
    int c = t / 10, kk = t - c * 10;
    int g = c >> 2, j = c & 3;
    uint32_t v = 0;
    if (c < C) {
        if (kk < 9) v = packh2(We[(2 * kk) * C + c], We[(2 * kk + 1) * C + c]);
        else v = __float_as_uint(att[c]);
    }
    WeT[g * 40 + j * 10 + kk] = v;
}

// ---------- combine Wl|Wr into padded Wc [K x NP], biases into bc [NP] ----------
__global__ void k_combine_w(const float* __restrict__ Wl, const float* __restrict__ bl,
                            const float* __restrict__ Wr, const float* __restrict__ br,
                            float* __restrict__ Wc, float* __restrict__ bc,
                            int K, int C, int NP) {
    int t = blockIdx.x * blockDim.x + threadIdx.x;
    if (t < K * NP) {
        int k = t / NP, n = t - k * NP;
        float v = 0.0f;
        if (n < C) v = Wl[k * C + n];
        else if (n < 2 * C) v = Wr[k * C + n - C];
        Wc[t] = v;
    }
    if (t < NP) {
        float v = 0.0f;
        if (t < C) v = bl[t];
        else if (t < 2 * C) v = br[t - C];
        bc[t] = v;
    }
}

// ---------- tiled dual GEMM -> xl16/xr16 (packed fp16, padded pitch RL) ----------
template <int KK, int NP, int C, int RL>
__global__ void __launch_bounds__(256)
k_gemm_dual(const float* __restrict__ A, const float* __restrict__ Wc,
            const float* __restrict__ bc,
            uint32_t* __restrict__ xl16, uint32_t* __restrict__ xr16) {
    constexpr int BM = 64, BN = 64, BK = 16;
    __shared__ float As[BK][BM];
    __shared__ float Ws[BK][BN];
    const int tidx = threadIdx.x;
    const int tx = tidx & 15;
    const int ty = tidx >> 4;
    const int m0 = blockIdx.x * BM;
    const int n0 = blockIdx.y * BN;

    float acc[4][4];
#pragma unroll
    for (int i2 = 0; i2 < 4; i2++)
#pragma unroll
        for (int j2 = 0; j2 < 4; j2++) acc[i2][j2] = 0.0f;

    for (int k0 = 0; k0 < KK; k0 += BK) {
        {
            int m = tidx >> 2;
            int kq = (tidx & 3) * 4;
            float4 v = make_float4(0.f, 0.f, 0.f, 0.f);
            if (m0 + m < NN && k0 + kq < KK)
                v = *(const float4*)(A + (size_t)(m0 + m) * KK + k0 + kq);
            As[kq + 0][m] = v.x; As[kq + 1][m] = v.y;
            As[kq + 2][m] = v.z; As[kq + 3][m] = v.w;
        }
        {
            int k = tidx >> 4;
            int nq = (tidx & 15) * 4;
            float4 v = make_float4(0.f, 0.f, 0.f, 0.f);
            if (k0 + k < KK)
                v = *(const float4*)(Wc + (size_t)(k0 + k) * NP + n0 + nq);
            *(float4*)&Ws[k][nq] = v;
        }
        __syncthreads();
#pragma unroll
        for (int k = 0; k < BK; k++) {
            float a[4], b[4];
            *(float4*)a = *(const float4*)&As[k][ty * 4];
            *(float4*)b = *(const float4*)&Ws[k][tx * 4];
#pragma unroll
            for (int i2 = 0; i2 < 4; i2++)
#pragma unroll
                for (int j2 = 0; j2 < 4; j2++) acc[i2][j2] += a[i2] * b[j2];
        }
        __syncthreads();
    }

    const int n = n0 + tx * 4;
    float4 bcv = *(const float4*)(bc + n);
#pragma unroll
    for (int i2 = 0; i2 < 4; i2++) {
        int m = m0 + ty * 4 + i2;
        if (m >= NN) continue;
        float4 o = make_float4(acc[i2][0] + bcv.x, acc[i2][1] + bcv.y,
                               acc[i2][2] + bcv.z, acc[i2][3] + bcv.w);
        uint2 p;
        p.x = packh2(o.x, o.y);
        p.y = packh2(o.z, o.w);
        if (n < C)          *(uint2*)(xl16 + (size_t)m * RL + n / 2) = p;
        else if (n < 2 * C) *(uint2*)(xr16 + (size_t)m * RL + (n - C) / 2) = p;
    }
}

// ---------- edge-parallel scores, UNPINNED (R2 structure, FULL unroll) ----------
template <int C>
__global__ void __launch_bounds__(256)
k_score_np(const int* __restrict__ csr_src, const int* __restrict__ csr_dst,
           const uint32_t* __restrict__ eaa, const uint32_t* __restrict__ WeT,
           const uint32_t* __restrict__ xl16, const uint32_t* __restrict__ xr16,
           float* __restrict__ scores) {
    constexpr int RL = ((C / 2) + 3) & ~3;   // padded dwords per row
    int pos = blockIdx.x * blockDim.x + threadIdx.x;
    if (pos >= ET) return;
    int s = csr_src[pos];
    int d = csr_dst[pos];

    uint32_t lw[RL], rw[RL];
    const uint4* pl = (const uint4*)(xl16 + (size_t)s * RL);
    const uint4* pr = (const uint4*)(xr16 + (size_t)d * RL);
#pragma unroll
    for (int i = 0; i < RL / 4; i++) *(uint4*)&lw[4 * i] = pl[i];
#pragma unroll
    for (int i = 0; i < RL / 4; i++) *(uint4*)&rw[4 * i] = pr[i];
    const uint32_t* pe = eaa + (size_t)pos * 12;
    uint4 e0 = *(const uint4*)pe;
    uint4 e1 = *(const uint4*)(pe + 4);
    uint32_t e8 = pe[8];
    uint32_t ean[9] = {e0.x, e0.y, e0.z, e0.w, e1.x, e1.y, e1.z, e1.w, e8};

    float score = 0.0f;
#pragma unroll
    for (int g = 0; g < C / 4; g++) {        // FULL unroll: static reg indices
        const uint32_t* wg = WeT + g * 40;   // wave-uniform -> scalar loads
        uint32_t u0 = pkadd(lw[2 * g], rw[2 * g]);
        uint32_t u1 = pkadd(lw[2 * g + 1], rw[2 * g + 1]);
        float2 f0 = uph(u0), f1 = uph(u1);
        float lv[4] = {f0.x, f0.y, f1.x, f1.y};
#pragma unroll
        for (int j = 0; j < 4; j++) {
            float w = 0.0f;
#pragma unroll
            for (int kk = 0; kk < 9; kk++) w = fdot2u(ean[kk], wg[j * 10 + kk], w);
            float u = lv[j] + w;
            float h = fmaxf(u, NEG_SLOPE * u);
            score = fmaf(__uint_as_float(wg[j * 10 + 9]), h, score);
        }
    }
    scores[pos] = score;
}

// ---------- edge-parallel scores, PINNED preload (kept for C=200) ----------
template <int C>
__global__ void __launch_bounds__(256, 2)
k_score_p(const int* __restrict__ csr_src, const int* __restrict__ csr_dst,
          const uint32_t* __restrict__ eaa, const uint32_t* __restrict__ WeT,
          const uint32_t* __restrict__ xl16, const uint32_t* __restrict__ xr16,
          float* __restrict__ scores) {
    constexpr int RL = ((C / 2) + 3) & ~3;
    int pos = blockIdx.x * blockDim.x + threadIdx.x;
    if (pos >= ET) return;
    int s = csr_src[pos];
    int d = csr_dst[pos];

    uint32_t lw[RL], rw[RL];
    const uint4* pl = (const uint4*)(xl16 + (size_t)s * RL);
    const uint4* pr = (const uint4*)(xr16 + (size_t)d * RL);
#pragma unroll
    for (int i = 0; i < RL / 4; i++) *(uint4*)&lw[4 * i] = pl[i];
#pragma unroll
    for (int i = 0; i < RL / 4; i++) *(uint4*)&rw[4 * i] = pr[i];
    const uint32_t* pe = eaa + (size_t)pos * 12;
    uint4 e0 = *(const uint4*)pe;
    uint4 e1 = *(const uint4*)(pe + 4);
    uint32_t e8 = pe[8];
    __builtin_amdgcn_sched_barrier(0);   // pin: loads issued before compute

    uint32_t ean[9] = {e0.x, e0.y, e0.z, e0.w, e1.x, e1.y, e1.z, e1.w, e8};

    float score = 0.0f;
#pragma unroll
    for (int g = 0; g < C / 4; g++) {
        const uint32_t* wg = WeT + g * 40;
        uint32_t u0 = pkadd(lw[2 * g], rw[2 * g]);
        uint32_t u1 = pkadd(lw[2 * g + 1], rw[2 * g + 1]);
        float2 f0 = uph(u0), f1 = uph(u1);
        float lv[4] = {f0.x, f0.y, f1.x, f1.y};
#pragma unroll
        for (int j = 0; j < 4; j++) {
            float w = 0.0f;
#pragma unroll
            for (int kk = 0; kk < 9; kk++) w = fdot2u(ean[kk], wg[j * 10 + kk], w);
            float u = lv[j] + w;
            float h = fmaxf(u, NEG_SLOPE * u);
            score = fmaf(__uint_as_float(wg[j * 10 + 9]), h, score);
        }
    }
    scores[pos] = score;
}

// ---------- per-node exact softmax + aggregation from fp16 rows ----------
// Pass-2 gather: 4-buffer rotation, 16-edge lookahead, pinned regions.
template <int C, int VEC, int RELU>
__global__ void __launch_bounds__(256)
k_fin(const int* __restrict__ rowptr, const int* __restrict__ csr_src,
      const float* __restrict__ scores, const uint32_t* __restrict__ xl16,
      const float* __restrict__ bias, float* __restrict__ out) {
    constexpr int DW = VEC / 2;              // dwords per lane per row
    constexpr int RL = ((C / 2) + 3) & ~3;   // row pitch in dwords
    constexpr int NL = C / VEC;
    const int lane = threadIdx.x & 63;
    int wid = blockIdx.x * (blockDim.x >> 6) + (threadIdx.x >> 6);
    int nw = gridDim.x * (blockDim.x >> 6);
    const bool act = lane < NL;

    float bv[VEC];
    if (act) {
#pragma unroll
        for (int j = 0; j < VEC; j++) bv[j] = bias[lane * VEC + j];
    } else {
#pragma unroll
        for (int j = 0; j < VEC; j++) bv[j] = 0.f;
    }

    auto ldrow = [&](uint32_t (&buf)[DW], int node) {
        if (act) {
            if constexpr (DW == 2) {
                uint2 v = *(const uint2*)(xl16 + (size_t)node * RL + lane * 2);
                buf[0] = v.x; buf[1] = v.y;
            } else {
                buf[0] = xl16[(size_t)node * RL + lane];
            }
        } else {
#pragma unroll
            for (int q = 0; q < DW; q++) buf[q] = 0;
        }
    };

    for (int i = wid; i < NN; i += nw) {
        int beg = __builtin_amdgcn_readfirstlane(rowptr[i]);
        int end = __builtin_amdgcn_readfirstlane(rowptr[i + 1]);
        float s_self = scores[EE + i];

        // pass 1: exact max
        float m = s_self;
        for (int cs = beg; cs < end; cs += 64) {
            int cnt = end - cs; if (cnt > 64) cnt = 64;
            float sc = (lane < cnt) ? scores[cs + lane] : -INFINITY;
#pragma unroll
            for (int off = 32; off; off >>= 1) sc = fmaxf(sc, __shfl_xor(sc, off, 64));
            m = fmaxf(m, sc);
        }

        // self-loop contribution
        float acc[VEC];
        float pes = __expf(s_self - m);
        float z = pes;
        {
            uint32_t w[DW];
            ldrow(w, i);
#pragma unroll
            for (int q = 0; q < DW; q++) {
                float2 f = uph(w[q]);
                acc[2 * q] = pes * f.x;
                acc[2 * q + 1] = pes * f.y;
            }
        }

        // pass 2: exp + denom + aggregation (4-buffer rotation, 16-edge lookahead)
        for (int cs = beg; cs < end; cs += 64) {
            int cnt = end - cs; if (cnt > 64) cnt = 64;
            float sc = (lane < cnt) ? scores[cs + lane] : -INFINITY;
            int srcl = (lane < cnt) ? csr_src[cs + lane] : 0;
            float pe = __expf(sc - m);
            float zc = pe;
#pragma unroll
            for (int off = 32; off; off >>= 1) zc += __shfl_xor(zc, off, 64);
            z += zc;

            uint32_t A[4][DW], B4[4][DW], C4[4][DW], D4[4][DW];
            auto LD4 = [&](uint32_t (&buf)[4][DW], int t0) {
#pragma unroll
                for (int q = 0; q < 4; q++) {
                    int t = t0 + q;
                    if (t < cnt) {
                        int sx = __builtin_amdgcn_readlane(srcl, t);
                        ldrow(buf[q], sx);
                    }
                }
            };
            auto USE4 = [&](uint32_t (&buf)[4][DW], int t0) {
#pragma unroll
                for (int q = 0; q < 4; q++) {
                    int t = t0 + q;
                    if (t < cnt) {
                        float a = rlanef(pe, t);
#pragma unroll
                        for (int qq = 0; qq < DW; qq++) {
                            float2 f = uph(buf[q][qq]);
                            acc[2 * qq] = fmaf(a, f.x, acc[2 * qq]);
                            acc[2 * qq + 1] = fmaf(a, f.y, acc[2 * qq + 1]);
                        }
                    }
                }
            };
            // prologue: 16 edges in flight before first use
            LD4(A, 0); LD4(B4, 4); LD4(C4, 8); LD4(D4, 12);
            __builtin_amdgcn_sched_barrier(0);
            for (int t0 = 0; t0 < cnt; t0 += 16) {
                USE4(A, t0);
                if (t0 + 16 < cnt) LD4(A, t0 + 16);
                __builtin_amdgcn_sched_barrier(0);
                USE4(B4, t0 + 4);
                if (t0 + 20 < cnt) LD4(B4, t0 + 20);
                __builtin_amdgcn_sched_barrier(0);
                USE4(C4, t0 + 8);
                if (t0 + 24 < cnt) LD4(C4, t0 + 24);
                __builtin_amdgcn_sched_barrier(0);
                USE4(D4, t0 + 12);
                if (t0 + 28 < cnt) LD4(D4, t0 + 28);
                __builtin_amdgcn_sched_barrier(0);
            }
        }

        float rz = 1.0f / z;
        if (act) {
            float o[VEC];
#pragma unroll
            for (int j = 0; j < VEC; j++) {
                o[j] = acc[j] * rz + bv[j];
                if (RELU) o[j] = fmaxf(o[j], 0.0f);
            }
            if constexpr (VEC == 4) {
                *(float4*)(out + (size_t)i * C + lane * 4) = make_float4(o[0], o[1], o[2], o[3]);
            } else {
                *(float2*)(out + (size_t)i * C + lane * 2) = make_float2(o[0], o[1]);
            }
        }
    }
}

// ---------- mean pooling per graph (batch_ids sorted); relu fused; 4-wide MLP ----------
__global__ void k_pool(const float* __restrict__ h, const int* __restrict__ batch,
                       float* __restrict__ pooled) {
    int g = blockIdx.x;
    int lo = 0, hi = NN;
    while (lo < hi) { int mid = (lo + hi) >> 1; if (batch[mid] < g) lo = mid + 1; else hi = mid; }
    int start = lo;
    lo = start; hi = NN;
    while (lo < hi) { int mid = (lo + hi) >> 1; if (batch[mid] < g + 1) lo = mid + 1; else hi = mid; }
    int end = lo;
    float cnt = (float)(end - start);
    int c = threadIdx.x;
    if (c < 200) {
        float a0 = 0.f, a1 = 0.f, a2 = 0.f, a3 = 0.f;
        int i = start;
        for (; i + 4 <= end; i += 4) {
            float v0 = h[(size_t)(i + 0) * 200 + c];
            float v1 = h[(size_t)(i + 1) * 200 + c];
            float v2 = h[(size_t)(i + 2) * 200 + c];
            float v3 = h[(size_t)(i + 3) * 200 + c];
            a0 += fmaxf(v0, 0.0f); a1 += fmaxf(v1, 0.0f);
            a2 += fmaxf(v2, 0.0f); a3 += fmaxf(v3, 0.0f);
        }
        for (; i < end; i++) a0 += fmaxf(h[(size_t)i * 200 + c], 0.0f);
        pooled[g * 200 + c] = ((a0 + a1) + (a2 + a3)) / fmaxf(cnt, 1.0f);
    }
}

// ---------- small dense layers on [G, *] ----------
__global__ void k_mlp(const float* __restrict__ X, const float* __restrict__ W,
                      const float* __restrict__ b, float* __restrict__ Y,
                      int Cin, int Cout, int do_relu) {
    int t = blockIdx.x * blockDim.x + threadIdx.x;
    if (t >= GG * Cout) return;
    int g = t / Cout, j = t - g * Cout;
    const float* xrow = X + (size_t)g * Cin;
    float acc = b[j];
#pragma unroll 4
    for (int k = 0; k < Cin; k++) acc += xrow[k] * W[k * Cout + j];
    if (do_relu) acc = fmaxf(acc, 0.0f);
    Y[t] = acc;
}

extern "C" void kernel_launch(void* const* d_in, const int* in_sizes, int n_in,
                              void* d_out, int out_size, void* d_ws, size_t ws_size,
                              hipStream_t stream) {
    const float* x   = (const float*)d_in[0];
    const int*   ei  = (const int*)d_in[1];
    const float* ea  = (const float*)d_in[2];
    const int*   bat = (const int*)d_in[3];
    const float* W1l = (const float*)d_in[4];  const float* b1l = (const float*)d_in[5];
    const float* W1r = (const float*)d_in[6];  const float* b1r = (const float*)d_in[7];
    const float* W1e = (const float*)d_in[8];
    const float* a1  = (const float*)d_in[9];  const float* c1  = (const float*)d_in[10];
    const float* W2l = (const float*)d_in[11]; const float* b2l = (const float*)d_in[12];
    const float* W2r = (const float*)d_in[13]; const float* b2r = (const float*)d_in[14];
    const float* W2e = (const float*)d_in[15];
    const float* a2  = (const float*)d_in[16]; const float* c2  = (const float*)d_in[17];
    const float* W3  = (const float*)d_in[18]; const float* b3  = (const float*)d_in[19];
    const float* F1  = (const float*)d_in[20]; const float* bf1 = (const float*)d_in[21];
    const float* F2  = (const float*)d_in[22]; const float* bf2 = (const float*)d_in[23];
    const float* F3  = (const float*)d_in[24]; const float* bf3 = (const float*)d_in[25];

    const int* srcv = ei;        // edge_index[0]
    const int* dstv = ei + EE;   // edge_index[1]

    float* W = (float*)d_ws;
    size_t off = 0;
    int*      hist    = (int*)(W + off); off += NN;
    float*    h1      = W + off; off += (size_t)NN * 100;
    float*    h2      = W + off; off += (size_t)NN * 200;
    int*      rowptr  = (int*)(W + off); off += NN + 4;
    int*      cursor  = (int*)(W + off); off += NN;
    int*      bsum    = (int*)(W + off); off += 256;
    float*    scores  = W + off; off += ET;
    int*      csr_src = (int*)(W + off); off += ET;
    int*      csr_dst = (int*)(W + off); off += ET;
    uint32_t* eaa     = (uint32_t*)(W + off); off += (size_t)ET * 12;
    uint32_t* xl16    = (uint32_t*)(W + off); off += (size_t)NN * 100;
    uint32_t* xr16    = (uint32_t*)(W + off); off += (size_t)NN * 100;
    uint32_t* WeT1    = (uint32_t*)(W + off); off += 26 * 40;
    uint32_t* WeT2    = (uint32_t*)(W + off); off += 50 * 40;
    float*    Wc1     = W + off; off += 16 * 256;
    float*    bc1     = W + off; off += 256;
    float*    Wc2     = W + off; off += 100 * 448;
    float*    bc2     = W + off; off += 448;
    float*    pooled  = W + off; off += (size_t)GG * 200;
    float*    p400    = W + off; off += (size_t)GG * 400;
    float*    y1      = W + off; off += (size_t)GG * 200;
    float*    y2      = W + off; off += (size_t)GG * 100;
    (void)ws_size; (void)n_in; (void)in_sizes; (void)out_size;

    const int B = 256;
    const int NODEB = 12500;   // 50000 waves, 1 node each

    // ---- degree histogram + CSR by dst; scatter also packs ea + src/dst ----
    hipMemsetAsync(hist, 0, (size_t)NN * sizeof(int), stream);
    k_hist<<<(EE + B - 1) / B, B, 0, stream>>>(dstv, hist);
    k_scan_a<<<NB, 256, 0, stream>>>(hist, bsum);
    k_scan_b<<<1, 256, 0, stream>>>(bsum, rowptr);
    k_scan_c<<<NB, 256, 0, stream>>>(hist, bsum, rowptr, cursor);
    k_scatter<<<(EE + B - 1) / B, B, 0, stream>>>(srcv, dstv, ea, cursor, csr_src, csr_dst, eaa);
    k_loop2<<<NODEB, B, 0, stream>>>(rowptr, eaa, csr_src, csr_dst);

    // ---- weight prep ----
    k_pack_wet<<<(104 * 10 + B - 1) / B, B, 0, stream>>>(W1e, a1, WeT1, 100, 104);
    k_pack_wet<<<(200 * 10 + B - 1) / B, B, 0, stream>>>(W2e, a2, WeT2, 200, 200);
    k_combine_w<<<(16 * 256 + B - 1) / B, B, 0, stream>>>(W1l, b1l, W1r, b1r, Wc1, bc1, 16, 100, 256);
    k_combine_w<<<(100 * 448 + B - 1) / B, B, 0, stream>>>(W2l, b2l, W2r, b2r, Wc2, bc2, 100, 200, 448);

    // ---- GAT layer 1: 16 -> 100 (RL = 52; pad dwords never read) ----
    {
        dim3 grid((NN + 63) / 64, 256 / 64);
        k_gemm_dual<16, 256, 100, 52><<<grid, 256, 0, stream>>>(x, Wc1, bc1, xl16, xr16);
    }
    k_score_np<100><<<(ET + B - 1) / B, B, 0, stream>>>(csr_src, csr_dst, eaa, WeT1, xl16, xr16, scores);
    k_fin<100, 2, 1><<<NODEB, B, 0, stream>>>(rowptr, csr_src, scores, xl16, c1, h1);

    // ---- GAT layer 2: 100 -> 200 (RL = 100) ----
    {
        dim3 grid((NN + 63) / 64, 448 / 64);
        k_gemm_dual<100, 448, 200, 100><<<grid, 256, 0, stream>>>(h1, Wc2, bc2, xl16, xr16);
    }
    k_score_p<200><<<(ET + B - 1) / B, B, 0, stream>>>(csr_src, csr_dst, eaa, WeT2, xl16, xr16, scores);
    k_fin<200, 4, 0><<<NODEB, B, 0, stream>>>(rowptr, csr_src, scores, xl16, c2, h2);

    // ---- pool (mean over graph, relu fused) then W3 + FFN ----
    k_pool<<<GG, 256, 0, stream>>>(h2, bat, pooled);
    k_mlp<<<(GG * 400 + B - 1) / B, B, 0, stream>>>(pooled, W3, b3, p400, 200, 400, 0);
    k_mlp<<<(GG * 200 + B - 1) / B, B, 0, stream>>>(p400, F1, bf1, y1, 400, 200, 1);
    k_mlp<<<(GG * 100 + B - 1) / B, B, 0, stream>>>(y1, F2, bf2, y2, 200, 100, 1);
    k_mlp<<<(GG * 100 + B - 1) / B, B, 0, stream>>>(y2, F3, bf3, (float*)d_out, 100, 100, 0);
}